// Round 17
// baseline (403.637 us; speedup 1.0000x reference)
//
#include <hip/hip_runtime.h>
#include <hip/hip_fp16.h>
#include <cfloat>

#define BROWS 16384

typedef float f32x4 __attribute__((ext_vector_type(4)));
typedef _Float16 f16x8 __attribute__((ext_vector_type(8)));

// ---------- wave helpers ----------
__device__ __forceinline__ float wsum64(float v) {
#pragma unroll
  for (int off = 32; off; off >>= 1) v += __shfl_xor(v, off);
  return v;
}
__device__ __forceinline__ float wmax64(float v) {
#pragma unroll
  for (int off = 32; off; off >>= 1) v = fmaxf(v, __shfl_xor(v, off));
  return v;
}
__device__ __forceinline__ float gsum16(float v) {
#pragma unroll
  for (int off = 1; off < 16; off <<= 1) v += __shfl_xor(v, off);
  return v;
}

__device__ __forceinline__ float gelu_exact(float y) {
  return 0.5f * y * (1.f + erff(y * 0.70710678118654752f));
}

// fp16 2-limb split: v ~= h0 + 2^-11 * h1, residual <= 2^-24 |v|
__device__ __forceinline__ void split2(float v, unsigned short& o0, unsigned short& o1) {
  const _Float16 h0 = (_Float16)v;
  const float r = (v - (float)h0) * 2048.0f;
  const _Float16 h1 = (_Float16)r;
  o0 = __builtin_bit_cast(unsigned short, h0);
  o1 = __builtin_bit_cast(unsigned short, h1);
}

// async global -> LDS, 16B per lane, dest = wave-uniform base + lane*16
__device__ __forceinline__ void gll16(const unsigned short* g, unsigned short* l) {
  __builtin_amdgcn_global_load_lds(
      (const __attribute__((address_space(1))) unsigned int*)g,
      (__attribute__((address_space(3))) unsigned int*)l, 16, 0, 0);
}

// Combined swizzled plane format (2 fp16 limbs):
//   buf[(r*KT + kt)*64 + p*8 + s], physical chunk p = c ^ (r&7);
//   c 0..3 = limb0, c 4..7 = limb1. Conflict-free ds_read_b128.
__device__ __forceinline__ void write_chunks(
    unsigned short* __restrict__ P, size_t row, int KT, int kt, int c,
    const float* vals8) {
  unsigned short h0[8], h1[8];
#pragma unroll
  for (int s = 0; s < 8; ++s) split2(vals8[s], h0[s], h1[s]);
  const int r7 = (int)(row & 7);
  const size_t o = ((size_t)row * KT + kt) * 64;
  *(uint4*)&P[o + (size_t)((c ^ r7) * 8)] = *(const uint4*)h0;
  *(uint4*)&P[o + (size_t)(((4 + c) ^ r7) * 8)] = *(const uint4*)h1;
}

// ---------- 0) prep: all weight/x splits in one launch ----------
__device__ __forceinline__ void split_w_body(
    const float* __restrict__ W, unsigned short* __restrict__ P,
    unsigned idx, int Nreal, int Kreal, int KT) {
  const unsigned ipr = (unsigned)(KT * 4);
  const unsigned row = idx / ipr;
  const unsigned item = idx - row * ipr;
  const int kt = item >> 2, c = item & 3;
  float v[8];
#pragma unroll
  for (int s = 0; s < 8; ++s) {
    const int k = kt * 32 + c * 8 + s;
    v[s] = ((int)row < Nreal && k < Kreal) ? W[(size_t)row * Kreal + k] : 0.f;
  }
  write_chunks(P, row, KT, kt, c, v);
}

__global__ __launch_bounds__(256) void prep_kernel(
    const float* __restrict__ x,
    const float* __restrict__ W1, unsigned short* __restrict__ P1,
    const float* __restrict__ W2, unsigned short* __restrict__ P2,
    const float* __restrict__ vol_w, const float* __restrict__ trend_w,
    const float* __restrict__ mom_w, const float* __restrict__ reg_w,
    unsigned short* __restrict__ Pe,
    const float* __restrict__ W3, float* __restrict__ Wt,
    const float* __restrict__ vol_b, const float* __restrict__ trend_b,
    const float* __restrict__ mom_b, const float* __restrict__ reg_b,
    float* __restrict__ benc,
    unsigned short* __restrict__ gip) {
  const unsigned bid = blockIdx.x;
  const int t = threadIdx.x;
  if (bid < 400) {        // W1: Npad=1280, KT=20
    split_w_body(W1, P1, bid * 256 + t, 1160, 580, 20);
  } else if (bid < 780) { // W2: Npad=640, KT=38
    split_w_body(W2, P2, (bid - 400) * 256 + t, 580, 1160, 38);
  } else if (bid < 812) { // Wenc: Npad=128, KT=16 (concat 4 branch 16x512)
    const unsigned idx = (bid - 780) * 256 + t;  // < 8192 = 128*64
    const unsigned row = idx >> 6;
    const unsigned item = idx & 63;
    const int kt = (int)(item >> 2), c = (int)(item & 3);
    float v[8];
    const float* wsrc = nullptr;
    if (row < 64) {
      const int br = (int)(row >> 4);
      wsrc = (br == 0) ? vol_w : (br == 1) ? trend_w : (br == 2) ? mom_w : reg_w;
      wsrc += (size_t)(row & 15) * 512;
    }
#pragma unroll
    for (int s = 0; s < 8; ++s) {
      const int k = kt * 32 + c * 8 + s;
      v[s] = wsrc ? wsrc[k] : 0.f;
    }
    write_chunks(Pe, row, 16, kt, c, v);
  } else if (bid < 957) { // W3 transpose: Wt[k][n] = W3[n][k], 580x64
    const unsigned idx = (bid - 812) * 256 + t;  // < 37120
    const unsigned k = idx >> 6, n = idx & 63;
    Wt[k * 64 + n] = W3[(size_t)n * 580 + k];
  } else if (bid == 957) { // benc: concat branch biases
    if (t < 64) {
      const int br = t >> 4;
      const float* bsel = (br == 0) ? vol_b : (br == 1) ? trend_b : (br == 2) ? mom_b : reg_b;
      benc[t] = bsel[t & 15];
    }
  } else {                // x -> gi planes kt 0..15
    const unsigned idx = (bid - 958) * 256 + t;  // < 16384*64
    const unsigned row = idx >> 6;
    const unsigned item = idx & 63;
    const int kt = (int)(item >> 2), c = (int)(item & 3);
    const int kbase = kt * 32 + c * 8;
    float v[8];
    const float4 u0 = *(const float4*)(x + (size_t)row * 512 + kbase);
    const float4 u1 = *(const float4*)(x + (size_t)row * 512 + kbase + 4);
    v[0] = u0.x; v[1] = u0.y; v[2] = u0.z; v[3] = u0.w;
    v[4] = u1.x; v[5] = u1.y; v[6] = u1.z; v[7] = u1.w;
    write_chunks(gip, row, 20, kt, c, v);
  }
}

// ---------- 1) fp16x3 MFMA GEMM v8: 2-slot ring, d=1, 2 blocks/CU ----------
__global__ __launch_bounds__(512, 4) void gemm_fp16x3_v8(
    const unsigned short* __restrict__ Ap, const unsigned short* __restrict__ Bp,
    const float* __restrict__ bias, float* __restrict__ C,
    int N, int KT, int ldc, int nbx, int strideA, int strideB) {
  extern __shared__ __align__(16) unsigned short smem[];  // 2 * 16384 ushorts
  const int t = threadIdx.x;
  const int wg = (blockIdx.x & 7) * ((int)gridDim.x >> 3) + (blockIdx.x >> 3);
  const int bx = wg % nbx, by = wg / nbx;
  const int m0 = by * 128, n0 = bx * 128;
  const int w = t >> 6, l = t & 63;
  const int lr = l & 15, lc = l >> 4;
  const int wm = (w >> 2) * 64, wn = (w & 3) * 32;

  size_t aoff[2], boff[2];
#pragma unroll
  for (int c = 0; c < 2; ++c) {
    const int rb = w * 16 + c * 8;
    aoff[c] = (size_t)(m0 + rb + (l >> 3)) * (size_t)strideA + (size_t)((l & 7) * 8);
    boff[c] = (size_t)(n0 + rb + (l >> 3)) * (size_t)strideB + (size_t)((l & 7) * 8);
  }

  f32x4 accM[4][2], accL[4][2];
#pragma unroll
  for (int i = 0; i < 4; ++i)
#pragma unroll
    for (int j = 0; j < 2; ++j) {
      accM[i][j] = (f32x4){0.f, 0.f, 0.f, 0.f};
      accL[i][j] = (f32x4){0.f, 0.f, 0.f, 0.f};
    }

  auto stage = [&](int kt, int slot) {
    unsigned short* base = smem + slot * 16384;
    const size_t ko = (size_t)kt * 64;
#pragma unroll
    for (int c = 0; c < 2; ++c) {
      const int rb = w * 16 + c * 8;
      gll16(Ap + aoff[c] + ko, base + rb * 64);
      gll16(Bp + boff[c] + ko, base + 8192 + rb * 64);
    }
  };

  stage(0, 0);
  __builtin_amdgcn_sched_barrier(0);
  int cur = 0;
  for (int kt = 0; kt < KT; ++kt) {
    __builtin_amdgcn_sched_barrier(0);
    if (kt + 1 < KT) {
      stage(kt + 1, cur ^ 1);               // writes the OTHER slot
      __builtin_amdgcn_sched_barrier(0);    // pin: stage issued before the count
      asm volatile("s_waitcnt vmcnt(4)" ::: "memory");  // stage(kt) landed
    } else {
      asm volatile("s_waitcnt vmcnt(0)" ::: "memory");
    }
    __builtin_amdgcn_sched_barrier(0);
    __builtin_amdgcn_s_barrier();           // all waves' stage(kt) visible
    __builtin_amdgcn_sched_barrier(0);

    const unsigned short* base = smem + cur * 16384;
    f16x8 a0[4], a1[4], b0[2], b1[2];
#pragma unroll
    for (int i = 0; i < 4; ++i) {
      const int ar = wm + i * 16 + lr;
      const int r7 = ar & 7;
      a0[i] = *(const f16x8*)&base[ar * 64 + ((lc ^ r7) << 3)];
      a1[i] = *(const f16x8*)&base[ar * 64 + (((4 + lc) ^ r7) << 3)];
    }
#pragma unroll
    for (int j = 0; j < 2; ++j) {
      const int brj = wn + j * 16 + lr;
      const int r7 = brj & 7;
      b0[j] = *(const f16x8*)&base[8192 + brj * 64 + ((lc ^ r7) << 3)];
      b1[j] = *(const f16x8*)&base[8192 + brj * 64 + (((4 + lc) ^ r7) << 3)];
    }
    __builtin_amdgcn_s_setprio(1);
#pragma unroll
    for (int i = 0; i < 4; ++i)
#pragma unroll
      for (int j = 0; j < 2; ++j)
        accM[i][j] = __builtin_amdgcn_mfma_f32_16x16x32_f16(a0[i], b0[j], accM[i][j], 0, 0, 0);
#pragma unroll
    for (int i = 0; i < 4; ++i)
#pragma unroll
      for (int j = 0; j < 2; ++j)
        accL[i][j] = __builtin_amdgcn_mfma_f32_16x16x32_f16(a1[i], b0[j], accL[i][j], 0, 0, 0);
#pragma unroll
    for (int i = 0; i < 4; ++i)
#pragma unroll
      for (int j = 0; j < 2; ++j)
        accL[i][j] = __builtin_amdgcn_mfma_f32_16x16x32_f16(a0[i], b1[j], accL[i][j], 0, 0, 0);
    __builtin_amdgcn_s_setprio(0);
    __builtin_amdgcn_sched_barrier(0);
    __builtin_amdgcn_s_barrier();           // WAR: all done reading cur
    __builtin_amdgcn_sched_barrier(0);      // pin: next iter's stage stays below
    cur ^= 1;
  }
  // epilogue: D layout col(lane&15)=n, row((lane>>4)*4+reg)=m
#pragma unroll
  for (int j = 0; j < 2; ++j) {
    const int n = n0 + wn + j * 16 + lr;
    if (n < N) {
      const float bz = bias[n];
#pragma unroll
      for (int i = 0; i < 4; ++i) {
        const int mb = m0 + wm + i * 16 + lc * 4;
#pragma unroll
        for (int r = 0; r < 4; ++r)
          C[(size_t)(mb + r) * (size_t)ldc + n] =
              accM[i][j][r] + 0.00048828125f * accL[i][j][r] + bz;
      }
    }
  }
}

// ---------- 1b) encoder post: ReLU+LN16+router+nsc + gi tail planes ----------
__global__ __launch_bounds__(256) void enc_post(
    const float* __restrict__ mfraw,
    const float* __restrict__ vol_g, const float* __restrict__ vol_bb,
    const float* __restrict__ trend_g, const float* __restrict__ trend_bb,
    const float* __restrict__ mom_g, const float* __restrict__ mom_bb,
    const float* __restrict__ reg_g, const float* __restrict__ reg_bb,
    const float* __restrict__ rc1_w, const float* __restrict__ rc1_b,
    const float* __restrict__ rc2_w, const float* __restrict__ rc2_b,
    const float* __restrict__ ns1_w, const float* __restrict__ ns1_b,
    const float* __restrict__ ns2_w, const float* __restrict__ ns2_b,
    float* __restrict__ rp4, float* __restrict__ nsc,
    unsigned short* __restrict__ gip) {
  __shared__ float smf[16][64];
  __shared__ float shid[16][32];
  __shared__ float srp[16][4];
  const int t = threadIdx.x, w = t >> 6, e = t & 63;
  const int br = e >> 4;
  const int rowbase0 = blockIdx.x * 16;

  const float* gsel = (br == 0) ? vol_g : (br == 1) ? trend_g : (br == 2) ? mom_g : reg_g;
  const float* bbsel = (br == 0) ? vol_bb : (br == 1) ? trend_bb : (br == 2) ? mom_bb : reg_bb;
  const float gv = gsel[e & 15];
  const float bbv = bbsel[e & 15];
#pragma unroll
  for (int r = 0; r < 4; ++r) {
    const int row = w * 4 + r;
    const float raw = mfraw[(size_t)(rowbase0 + row) * 64 + e];
    const float v = fmaxf(raw, 0.f);
    const float mu = gsum16(v) * (1.f / 16.f);
    const float d = v - mu;
    const float var = gsum16(d * d) * (1.f / 16.f);
    smf[row][e] = d * (1.f / sqrtf(var + 1e-5f)) * gv + bbv;
  }
  __syncthreads();

  if (e < 32) {
#pragma unroll
    for (int r = 0; r < 4; ++r) {
      const int row = w * 4 + r;
      float h = rc1_b[e];
#pragma unroll 8
      for (int j = 0; j < 64; ++j) h += rc1_w[e * 64 + j] * smf[row][j];
      shid[row][e] = fmaxf(h, 0.f);
    }
  }
  __syncthreads();
  if (e < 16) {
    const int r = e >> 2, l = e & 3;
    const int row = w * 4 + r;
    float z = rc2_b[l];
#pragma unroll 8
    for (int j = 0; j < 32; ++j) z += rc2_w[l * 32 + j] * shid[row][j];
    float mx = z;
    mx = fmaxf(mx, __shfl_xor(mx, 1));
    mx = fmaxf(mx, __shfl_xor(mx, 2));
    const float ex = expf(z - mx);
    float s = ex;
    s += __shfl_xor(s, 1);
    s += __shfl_xor(s, 2);
    const float rp = ex / s;
    srp[row][l] = rp;
    rp4[(size_t)(rowbase0 + row) * 4 + l] = rp;
  }
  __syncthreads();
  if (e < 4) {
    const int row = w * 4 + e;
    const float rp0 = srp[row][0], rp1 = srp[row][1], rp2 = srp[row][2], rp3 = srp[row][3];
    float z = ns2_b[0];
#pragma unroll
    for (int i = 0; i < 16; ++i) {
      float h = ns1_b[i] + ns1_w[i * 4 + 0] * rp0 + ns1_w[i * 4 + 1] * rp1 +
                ns1_w[i * 4 + 2] * rp2 + ns1_w[i * 4 + 3] * rp3;
      z += ns2_w[i] * fmaxf(h, 0.f);
    }
    nsc[rowbase0 + row] = 1.f / (1.f + expf(-z));
  }
  __syncthreads();
  // gi tail planes (kt 16..19): 16 rows x 16 items = 256 -> one per thread
  {
    const int rib = t >> 4;
    const int item = t & 15;
    const int kt = 16 + (item >> 2), c = item & 3;
    const int kbase = kt * 32 + c * 8;
    const size_t grow = (size_t)rowbase0 + rib;
    float v[8];
#pragma unroll
    for (int s = 0; s < 8; ++s) {
      const int k = kbase + s;
      float f = 0.f;
      if (k < 576) f = smf[rib][k - 512];
      else if (k < 580) f = srp[rib][k - 576];
      v[s] = f;
    }
    write_chunks(gip, grow, 20, kt, c, v);
  }
}

// ---------- 2) tail v3: 8 rows/block, k-split GEMV with shared Wt pass ----------
__global__ __launch_bounds__(256) void tail_v3(
    const float* __restrict__ Zraw, const float* __restrict__ gamma,
    const float* __restrict__ beta, const float* __restrict__ Wt,
    const float* __restrict__ bias,
    const float* __restrict__ rp4, const float* __restrict__ nsc,
    const float* __restrict__ noise, const float* __restrict__ spec,
    float* __restrict__ out, float* __restrict__ pg, float* __restrict__ pl) {
  __shared__ __align__(16) float arowT[580][12];
  __shared__ float spart[4][8][64];
  __shared__ float sgp[4][64], slp[4][64];
  const int t = threadIdx.x, w = t >> 6, e = t & 63;

  // ph1: LN + GELU for this wave's 2 rows
#pragma unroll
  for (int rr = 0; rr < 2; ++rr) {
    const int r = w * 2 + rr;
    const int row = blockIdx.x * 8 + r;
    const float* zr = Zraw + (size_t)row * 580;
    float vals[10];
    float s = 0.f, ss = 0.f;
#pragma unroll
    for (int c = 0; c < 10; ++c) {
      const int k = e + c * 64;
      const float v = (k < 580) ? zr[k] : 0.f;
      vals[c] = v;
      s += v;
      ss += v * v;
    }
    s = wsum64(s);
    ss = wsum64(ss);
    const float mu = s * (1.f / 580.f);
    const float var = fmaxf(ss * (1.f / 580.f) - mu * mu, 0.f);
    const float rs = 1.f / sqrtf(var + 1e-5f);
#pragma unroll
    for (int c = 0; c < 10; ++c) {
      const int k = e + c * 64;
      if (k < 580)
        arowT[k][r] = gelu_exact((vals[c] - mu) * rs * gamma[k] + beta[k]);
    }
  }
  __syncthreads();

  // ph2: k-split GEMV
  float part[8] = {};
  const int k0 = w * 145;
#pragma unroll 4
  for (int kk = 0; kk < 145; ++kk) {
    const int k = k0 + kk;
    const float4 a0 = *(const float4*)&arowT[k][0];
    const float4 a1 = *(const float4*)&arowT[k][4];
    const float wv = Wt[k * 64 + e];
    part[0] = fmaf(a0.x, wv, part[0]);
    part[1] = fmaf(a0.y, wv, part[1]);
    part[2] = fmaf(a0.z, wv, part[2]);
    part[3] = fmaf(a0.w, wv, part[3]);
    part[4] = fmaf(a1.x, wv, part[4]);
    part[5] = fmaf(a1.y, wv, part[5]);
    part[6] = fmaf(a1.z, wv, part[6]);
    part[7] = fmaf(a1.w, wv, part[7]);
  }
#pragma unroll
  for (int r = 0; r < 8; ++r) spart[w][r][e] = part[r];
  __syncthreads();

  // ph3: finish this wave's 2 rows
  const float4 sp = *(const float4*)(spec + e * 4);
  const float bz = bias[e];
  float accg = 0.f, accl = 0.f;
#pragma unroll
  for (int rr = 0; rr < 2; ++rr) {
    const int r = w * 2 + rr;
    const int row = blockIdx.x * 8 + r;
    float c = bz + ((spart[0][r][e] + spart[1][r][e]) + (spart[2][r][e] + spart[3][r][e]));
    const float4 rp = *(const float4*)(rp4 + (size_t)row * 4);
    c += rp.x * sp.x + rp.y * sp.y + rp.z * sp.z + rp.w * sp.w;
    const float nv = noise[(size_t)row * 64 + e];
    const float noisy = c + nv * nsc[row];
    float v = noisy;
    int ix = e;
#pragma unroll
    for (int off = 32; off; off >>= 1) {
      const float ov = __shfl_xor(v, off);
      const int oi = __shfl_xor(ix, off);
      if (ov > v || (ov == v && oi < ix)) { v = ov; ix = oi; }
    }
    const float v1 = v;
    const int i1 = ix;
    float v2 = (e == i1) ? -FLT_MAX : noisy;
    int ix2 = e;
#pragma unroll
    for (int off = 32; off; off >>= 1) {
      const float ov = __shfl_xor(v2, off);
      const int oi = __shfl_xor(ix2, off);
      if (ov > v2 || (ov == v2 && oi < ix2)) { v2 = ov; ix2 = oi; }
    }
    const int i2 = ix2;
    if (e == 0) {
      const float texp = expf(v2 - v1);
      const float tw0 = 1.f / (1.f + texp);
      out[(size_t)row * 2 + 0] = tw0;
      out[(size_t)row * 2 + 1] = texp * tw0;
      out[32768 + (size_t)row * 2 + 0] = (float)i1;
      out[32768 + (size_t)row * 2 + 1] = (float)i2;
    }
    const float mx = wmax64(c);
    const float p = expf(c - mx);
    const float ssum = wsum64(p);
    accg += p / ssum;
    accl += (e == i1 || e == i2) ? 1.f : 0.f;
  }
  sgp[w][e] = accg;
  slp[w][e] = accl;
  __syncthreads();
  if (t < 64) {
    pg[blockIdx.x * 64 + t] = sgp[0][t] + sgp[1][t] + sgp[2][t] + sgp[3][t];
    pl[blockIdx.x * 64 + t] = slp[0][t] + slp[1][t] + slp[2][t] + slp[3][t];
  }
}

// ---------- 3) ln_gelu_split v4: register-resident, no LDS, no barriers ----------
// 1 wave = 1 row; lane owns CONTIGUOUS 8-elem chunks (chunk = lane + c*64,
// 145 real chunks = 1160 elems), so GELU+write_chunks run straight from the
// load registers. Two-pass stats via wave reduce (numerics identical to v3).
__global__ __launch_bounds__(256) void ln_gelu_split_v4(
    const float* __restrict__ Z, const float* __restrict__ gamma,
    const float* __restrict__ beta, unsigned short* __restrict__ P) {
  const int N = 1160, KT = 38;
  const int t = threadIdx.x, w = t >> 6, l = t & 63;
  const size_t row = (size_t)blockIdx.x * 4 + w;
  const float* zr = Z + row * N;
  float vals[3][8];
  float s = 0.f;
#pragma unroll
  for (int c = 0; c < 3; ++c) {
    const int ch = l + c * 64;
    if (ch < 145) {
      const float4 u0 = *(const float4*)(zr + ch * 8);
      const float4 u1 = *(const float4*)(zr + ch * 8 + 4);
      vals[c][0] = u0.x; vals[c][1] = u0.y; vals[c][2] = u0.z; vals[c][3] = u0.w;
      vals[c][4] = u1.x; vals[c][5] = u1.y; vals[c][6] = u1.z; vals[c][7] = u1.w;
      s += ((u0.x + u0.y) + (u0.z + u0.w)) + ((u1.x + u1.y) + (u1.z + u1.w));
    } else {
#pragma unroll
      for (int k = 0; k < 8; ++k) vals[c][k] = 0.f;
    }
  }
  s = wsum64(s);
  const float mu = s * (1.f / 1160.f);
  float q = 0.f;
#pragma unroll
  for (int c = 0; c < 3; ++c) {
    const int ch = l + c * 64;
    if (ch < 145) {
#pragma unroll
      for (int k = 0; k < 8; ++k) {
        const float d = vals[c][k] - mu;
        q += d * d;
      }
    }
  }
  q = wsum64(q);
  const float rstd = 1.f / sqrtf(q * (1.f / 1160.f) + 1e-5f);
#pragma unroll
  for (int c = 0; c < 3; ++c) {
    const int ch = l + c * 64;
    if (ch < 152) {
      float g[8];
      if (ch < 145) {
        const int kb = ch * 8;
#pragma unroll
        for (int k = 0; k < 8; ++k)
          g[k] = gelu_exact((vals[c][k] - mu) * rstd * gamma[kb + k] + beta[kb + k]);
      } else {
#pragma unroll
        for (int k = 0; k < 8; ++k) g[k] = 0.f;
      }
      write_chunks(P, row, KT, ch >> 2, ch & 3, g);
    }
  }
}

// ---------- 5) aux loss (hierarchical over 2048 block-partials) ----------
__global__ __launch_bounds__(1024) void loss_kernel2(
    const float* __restrict__ pg, const float* __restrict__ pl,
    float* __restrict__ out) {
  __shared__ float sgl[16][64], sll[16][64];
  const int t = threadIdx.x, w = t >> 6, e = t & 63;
  float g = 0.f, l = 0.f;
  for (int b = w; b < 2048; b += 16) {
    g += pg[b * 64 + e];
    l += pl[b * 64 + e];
  }
  sgl[w][e] = g;
  sll[w][e] = l;
  __syncthreads();
  if (t < 64) {
    float gg = 0.f, ll = 0.f;
#pragma unroll
    for (int i = 0; i < 16; ++i) { gg += sgl[i][t]; ll += sll[i][t]; }
    const float prob = gg * (1.f / 16384.f);
    const float ld = ll * (1.f / 16384.f);
    const float load_loss = 64.f * wsum64(prob * ld);
    const float sgs = wsum64(gg);
    const float mean = sgs * (1.f / 64.f);
    const float d = gg - mean;
    const float var = wsum64(d * d) * (1.f / 63.f);
    if (t == 0) out[65536] = 0.01f * load_loss + 0.01f * (var / mean);
  }
}

extern "C" void kernel_launch(void* const* d_in, const int* in_sizes, int n_in,
                              void* d_out, int out_size, void* d_ws, size_t ws_size,
                              hipStream_t stream) {
  (void)in_sizes; (void)n_in; (void)out_size; (void)ws_size;
  const float* x = (const float*)d_in[0];
  const float* noise = (const float*)d_in[1];
  const float* vol_w = (const float*)d_in[2];
  const float* vol_b = (const float*)d_in[3];
  const float* vol_g = (const float*)d_in[4];
  const float* vol_bb = (const float*)d_in[5];
  const float* trend_w = (const float*)d_in[6];
  const float* trend_b = (const float*)d_in[7];
  const float* trend_g = (const float*)d_in[8];
  const float* trend_bb = (const float*)d_in[9];
  const float* mom_w = (const float*)d_in[10];
  const float* mom_b = (const float*)d_in[11];
  const float* mom_g = (const float*)d_in[12];
  const float* mom_bb = (const float*)d_in[13];
  const float* reg_w = (const float*)d_in[14];
  const float* reg_b = (const float*)d_in[15];
  const float* reg_g = (const float*)d_in[16];
  const float* reg_bb = (const float*)d_in[17];
  const float* rc1_w = (const float*)d_in[18];
  const float* rc1_b = (const float*)d_in[19];
  const float* rc2_w = (const float*)d_in[20];
  const float* rc2_b = (const float*)d_in[21];
  const float* g1_w = (const float*)d_in[22];
  const float* g1_b = (const float*)d_in[23];
  const float* g1_g = (const float*)d_in[24];
  const float* g1_bb = (const float*)d_in[25];
  const float* g2_w = (const float*)d_in[26];
  const float* g2_b = (const float*)d_in[27];
  const float* g2_g = (const float*)d_in[28];
  const float* g2_bb = (const float*)d_in[29];
  const float* g3_w = (const float*)d_in[30];
  const float* g3_b = (const float*)d_in[31];
  const float* ns1_w = (const float*)d_in[32];
  const float* ns1_b = (const float*)d_in[33];
  const float* ns2_w = (const float*)d_in[34];
  const float* ns2_b = (const float*)d_in[35];
  const float* spec = (const float*)d_in[36];
  float* out = (float*)d_out;

  const size_t B = BROWS;
  float* ws = (float*)d_ws;
  float* rp4 = ws;                                    // B*4 f32
  float* nsc = rp4 + B * 4;                           // B f32
  float* z1 = nsc + B;                                // B*1160 f32
  unsigned short* gip = (unsigned short*)(z1 + B * 1160);  // B*1280 ush (KT=20)
  float* z2 = (float*)gip;                            // alias: B*580 f32 (gi dead after G1)
  unsigned short* z1p = gip + B * 1280;               // B*2432 ush (KT=38)
  unsigned short* w1p = z1p + B * 2432;               // 1280*1280 ush
  unsigned short* w2p = w1p + (size_t)1280 * 1280;    // 640*2432 ush
  unsigned short* wencp = w2p + (size_t)640 * 2432;   // 128*1024 ush
  float* wt = (float*)(wencp + 128 * 1024);           // 580*64 f32
  float* benc = wt + 580 * 64;                        // 64 f32
  float* pg = benc + 64;                              // 2048*64
  float* pl = pg + 2048 * 64;                         // 2048*64
  float* mfraw = pl + 2048 * 64;                      // B*64 f32

  hipFuncSetAttribute(reinterpret_cast<const void*>(gemm_fp16x3_v8),
                      hipFuncAttributeMaxDynamicSharedMemorySize, 65536);

  // prep: all splits + transposes (one launch)
  prep_kernel<<<5054, 256, 0, stream>>>(
      x, g1_w, w1p, g2_w, w2p, vol_w, trend_w, mom_w, reg_w, wencp,
      g3_w, wt, vol_b, trend_b, mom_b, reg_b, benc, gip);

  // encoder GEMM: [16384,512] x [64,512]^T -> mfraw ; A=gip (strideA 1280, KT=16)
  gemm_fp16x3_v8<<<128, 512, 65536, stream>>>(
      gip, wencp, benc, mfraw, 64, 16, 64, 1, 1280, 1024);

  // encoder post: ReLU+LN16+router+nsc + gi tail planes
  enc_post<<<1024, 256, 0, stream>>>(
      mfraw, vol_g, vol_bb, trend_g, trend_bb, mom_g, mom_bb, reg_g, reg_bb,
      rc1_w, rc1_b, rc2_w, rc2_b, ns1_w, ns1_b, ns2_w, ns2_b, rp4, nsc, gip);

  // G1: [16384,640] x [1280,640]^T -> z1
  gemm_fp16x3_v8<<<1280, 512, 65536, stream>>>(
      gip, w1p, g1_b, z1, 1160, 20, 1160, 10, 1280, 1280);
  ln_gelu_split_v4<<<4096, 256, 0, stream>>>(z1, g1_g, g1_bb, z1p);

  // G2: [16384,1216] x [640,1216]^T -> z2
  gemm_fp16x3_v8<<<640, 512, 65536, stream>>>(
      z1p, w2p, g2_b, z2, 580, 38, 580, 5, 2432, 2432);

  // tail: LN+GELU+G3-GEMV+noisy-top2+partials (8 rows/block, shared Wt pass)
  tail_v3<<<2048, 256, 0, stream>>>(
      z2, g2_g, g2_bb, wt, g3_b, rp4, nsc, noise, spec, out, pg, pl);
  loss_kernel2<<<1, 1024, 0, stream>>>(pg, pl, out);
}

// Round 18
// 357.331 us; speedup vs baseline: 1.1296x; 1.1296x over previous
//
#include <hip/hip_runtime.h>
#include <hip/hip_fp16.h>
#include <cfloat>

#define BROWS 16384

typedef float f32x4 __attribute__((ext_vector_type(4)));
typedef _Float16 f16x8 __attribute__((ext_vector_type(8)));

// ---------- wave helpers ----------
__device__ __forceinline__ float wsum64(float v) {
#pragma unroll
  for (int off = 32; off; off >>= 1) v += __shfl_xor(v, off);
  return v;
}
__device__ __forceinline__ float wmax64(float v) {
#pragma unroll
  for (int off = 32; off; off >>= 1) v = fmaxf(v, __shfl_xor(v, off));
  return v;
}
__device__ __forceinline__ float gsum16(float v) {
#pragma unroll
  for (int off = 1; off < 16; off <<= 1) v += __shfl_xor(v, off);
  return v;
}

// exact-GELU via branchless A&S 7.1.26 erf (max abs err 1.5e-7 ~ fp32 noise;
// replaces libm erff's divergent two-path ~50-op form with ~12 uniform ops)
__device__ __forceinline__ float gelu_exact(float y) {
  const float x = y * 0.70710678118654752f;
  const float ax = fabsf(x);
  const float t = 1.f / fmaf(0.3275911f, ax, 1.f);
  float p = fmaf(1.061405429f, t, -1.453152027f);
  p = fmaf(p, t, 1.421413741f);
  p = fmaf(p, t, -0.284496736f);
  p = fmaf(p, t, 0.254829592f);
  p = p * t;
  const float e = __expf(-ax * ax);
  const float er = fmaf(-p, e, 1.f);        // erf(|x|)
  const float erfx = copysignf(er, x);
  return 0.5f * y * (1.f + erfx);
}

// fp16 2-limb split: v ~= h0 + 2^-11 * h1, residual <= 2^-24 |v|
__device__ __forceinline__ void split2(float v, unsigned short& o0, unsigned short& o1) {
  const _Float16 h0 = (_Float16)v;
  const float r = (v - (float)h0) * 2048.0f;
  const _Float16 h1 = (_Float16)r;
  o0 = __builtin_bit_cast(unsigned short, h0);
  o1 = __builtin_bit_cast(unsigned short, h1);
}

// async global -> LDS, 16B per lane, dest = wave-uniform base + lane*16
__device__ __forceinline__ void gll16(const unsigned short* g, unsigned short* l) {
  __builtin_amdgcn_global_load_lds(
      (const __attribute__((address_space(1))) unsigned int*)g,
      (__attribute__((address_space(3))) unsigned int*)l, 16, 0, 0);
}

// Combined swizzled plane format (2 fp16 limbs):
//   buf[(r*KT + kt)*64 + p*8 + s], physical chunk p = c ^ (r&7);
//   c 0..3 = limb0, c 4..7 = limb1. Conflict-free ds_read_b128.
__device__ __forceinline__ void write_chunks(
    unsigned short* __restrict__ P, size_t row, int KT, int kt, int c,
    const float* vals8) {
  unsigned short h0[8], h1[8];
#pragma unroll
  for (int s = 0; s < 8; ++s) split2(vals8[s], h0[s], h1[s]);
  const int r7 = (int)(row & 7);
  const size_t o = ((size_t)row * KT + kt) * 64;
  *(uint4*)&P[o + (size_t)((c ^ r7) * 8)] = *(const uint4*)h0;
  *(uint4*)&P[o + (size_t)(((4 + c) ^ r7) * 8)] = *(const uint4*)h1;
}

// ---------- 0) prep: all weight/x splits in one launch ----------
__device__ __forceinline__ void split_w_body(
    const float* __restrict__ W, unsigned short* __restrict__ P,
    unsigned idx, int Nreal, int Kreal, int KT) {
  const unsigned ipr = (unsigned)(KT * 4);
  const unsigned row = idx / ipr;
  const unsigned item = idx - row * ipr;
  const int kt = item >> 2, c = item & 3;
  float v[8];
#pragma unroll
  for (int s = 0; s < 8; ++s) {
    const int k = kt * 32 + c * 8 + s;
    v[s] = ((int)row < Nreal && k < Kreal) ? W[(size_t)row * Kreal + k] : 0.f;
  }
  write_chunks(P, row, KT, kt, c, v);
}

__global__ __launch_bounds__(256) void prep_kernel(
    const float* __restrict__ x,
    const float* __restrict__ W1, unsigned short* __restrict__ P1,
    const float* __restrict__ W2, unsigned short* __restrict__ P2,
    const float* __restrict__ vol_w, const float* __restrict__ trend_w,
    const float* __restrict__ mom_w, const float* __restrict__ reg_w,
    unsigned short* __restrict__ Pe,
    const float* __restrict__ W3, float* __restrict__ Wt,
    const float* __restrict__ vol_b, const float* __restrict__ trend_b,
    const float* __restrict__ mom_b, const float* __restrict__ reg_b,
    float* __restrict__ benc,
    unsigned short* __restrict__ gip) {
  const unsigned bid = blockIdx.x;
  const int t = threadIdx.x;
  if (bid < 400) {        // W1: Npad=1280, KT=20
    split_w_body(W1, P1, bid * 256 + t, 1160, 580, 20);
  } else if (bid < 780) { // W2: Npad=640, KT=38
    split_w_body(W2, P2, (bid - 400) * 256 + t, 580, 1160, 38);
  } else if (bid < 812) { // Wenc: Npad=128, KT=16 (concat 4 branch 16x512)
    const unsigned idx = (bid - 780) * 256 + t;  // < 8192 = 128*64
    const unsigned row = idx >> 6;
    const unsigned item = idx & 63;
    const int kt = (int)(item >> 2), c = (int)(item & 3);
    float v[8];
    const float* wsrc = nullptr;
    if (row < 64) {
      const int br = (int)(row >> 4);
      wsrc = (br == 0) ? vol_w : (br == 1) ? trend_w : (br == 2) ? mom_w : reg_w;
      wsrc += (size_t)(row & 15) * 512;
    }
#pragma unroll
    for (int s = 0; s < 8; ++s) {
      const int k = kt * 32 + c * 8 + s;
      v[s] = wsrc ? wsrc[k] : 0.f;
    }
    write_chunks(Pe, row, 16, kt, c, v);
  } else if (bid < 957) { // W3 transpose: Wt[k][n] = W3[n][k], 580x64
    const unsigned idx = (bid - 812) * 256 + t;  // < 37120
    const unsigned k = idx >> 6, n = idx & 63;
    Wt[k * 64 + n] = W3[(size_t)n * 580 + k];
  } else if (bid == 957) { // benc: concat branch biases
    if (t < 64) {
      const int br = t >> 4;
      const float* bsel = (br == 0) ? vol_b : (br == 1) ? trend_b : (br == 2) ? mom_b : reg_b;
      benc[t] = bsel[t & 15];
    }
  } else {                // x -> gi planes kt 0..15
    const unsigned idx = (bid - 958) * 256 + t;  // < 16384*64
    const unsigned row = idx >> 6;
    const unsigned item = idx & 63;
    const int kt = (int)(item >> 2), c = (int)(item & 3);
    const int kbase = kt * 32 + c * 8;
    float v[8];
    const float4 u0 = *(const float4*)(x + (size_t)row * 512 + kbase);
    const float4 u1 = *(const float4*)(x + (size_t)row * 512 + kbase + 4);
    v[0] = u0.x; v[1] = u0.y; v[2] = u0.z; v[3] = u0.w;
    v[4] = u1.x; v[5] = u1.y; v[6] = u1.z; v[7] = u1.w;
    write_chunks(gip, row, 20, kt, c, v);
  }
}

// ---------- 1) fp16x3 MFMA GEMM v8: 2-slot ring, d=1, 2 blocks/CU ----------
__global__ __launch_bounds__(512, 4) void gemm_fp16x3_v8(
    const unsigned short* __restrict__ Ap, const unsigned short* __restrict__ Bp,
    const float* __restrict__ bias, float* __restrict__ C,
    int N, int KT, int ldc, int nbx, int strideA, int strideB) {
  extern __shared__ __align__(16) unsigned short smem[];  // 2 * 16384 ushorts
  const int t = threadIdx.x;
  const int wg = (blockIdx.x & 7) * ((int)gridDim.x >> 3) + (blockIdx.x >> 3);
  const int bx = wg % nbx, by = wg / nbx;
  const int m0 = by * 128, n0 = bx * 128;
  const int w = t >> 6, l = t & 63;
  const int lr = l & 15, lc = l >> 4;
  const int wm = (w >> 2) * 64, wn = (w & 3) * 32;

  size_t aoff[2], boff[2];
#pragma unroll
  for (int c = 0; c < 2; ++c) {
    const int rb = w * 16 + c * 8;
    aoff[c] = (size_t)(m0 + rb + (l >> 3)) * (size_t)strideA + (size_t)((l & 7) * 8);
    boff[c] = (size_t)(n0 + rb + (l >> 3)) * (size_t)strideB + (size_t)((l & 7) * 8);
  }

  f32x4 accM[4][2], accL[4][2];
#pragma unroll
  for (int i = 0; i < 4; ++i)
#pragma unroll
    for (int j = 0; j < 2; ++j) {
      accM[i][j] = (f32x4){0.f, 0.f, 0.f, 0.f};
      accL[i][j] = (f32x4){0.f, 0.f, 0.f, 0.f};
    }

  auto stage = [&](int kt, int slot) {
    unsigned short* base = smem + slot * 16384;
    const size_t ko = (size_t)kt * 64;
#pragma unroll
    for (int c = 0; c < 2; ++c) {
      const int rb = w * 16 + c * 8;
      gll16(Ap + aoff[c] + ko, base + rb * 64);
      gll16(Bp + boff[c] + ko, base + 8192 + rb * 64);
    }
  };

  stage(0, 0);
  __builtin_amdgcn_sched_barrier(0);
  int cur = 0;
  for (int kt = 0; kt < KT; ++kt) {
    __builtin_amdgcn_sched_barrier(0);
    if (kt + 1 < KT) {
      stage(kt + 1, cur ^ 1);               // writes the OTHER slot
      __builtin_amdgcn_sched_barrier(0);    // pin: stage issued before the count
      asm volatile("s_waitcnt vmcnt(4)" ::: "memory");  // stage(kt) landed
    } else {
      asm volatile("s_waitcnt vmcnt(0)" ::: "memory");
    }
    __builtin_amdgcn_sched_barrier(0);
    __builtin_amdgcn_s_barrier();           // all waves' stage(kt) visible
    __builtin_amdgcn_sched_barrier(0);

    const unsigned short* base = smem + cur * 16384;
    f16x8 a0[4], a1[4], b0[2], b1[2];
#pragma unroll
    for (int i = 0; i < 4; ++i) {
      const int ar = wm + i * 16 + lr;
      const int r7 = ar & 7;
      a0[i] = *(const f16x8*)&base[ar * 64 + ((lc ^ r7) << 3)];
      a1[i] = *(const f16x8*)&base[ar * 64 + (((4 + lc) ^ r7) << 3)];
    }
#pragma unroll
    for (int j = 0; j < 2; ++j) {
      const int brj = wn + j * 16 + lr;
      const int r7 = brj & 7;
      b0[j] = *(const f16x8*)&base[8192 + brj * 64 + ((lc ^ r7) << 3)];
      b1[j] = *(const f16x8*)&base[8192 + brj * 64 + (((4 + lc) ^ r7) << 3)];
    }
    __builtin_amdgcn_s_setprio(1);
#pragma unroll
    for (int i = 0; i < 4; ++i)
#pragma unroll
      for (int j = 0; j < 2; ++j)
        accM[i][j] = __builtin_amdgcn_mfma_f32_16x16x32_f16(a0[i], b0[j], accM[i][j], 0, 0, 0);
#pragma unroll
    for (int i = 0; i < 4; ++i)
#pragma unroll
      for (int j = 0; j < 2; ++j)
        accL[i][j] = __builtin_amdgcn_mfma_f32_16x16x32_f16(a1[i], b0[j], accL[i][j], 0, 0, 0);
#pragma unroll
    for (int i = 0; i < 4; ++i)
#pragma unroll
      for (int j = 0; j < 2; ++j)
        accL[i][j] = __builtin_amdgcn_mfma_f32_16x16x32_f16(a0[i], b1[j], accL[i][j], 0, 0, 0);
    __builtin_amdgcn_s_setprio(0);
    __builtin_amdgcn_sched_barrier(0);
    __builtin_amdgcn_s_barrier();           // WAR: all done reading cur
    __builtin_amdgcn_sched_barrier(0);      // pin: next iter's stage stays below
    cur ^= 1;
  }
  // epilogue: D layout col(lane&15)=n, row((lane>>4)*4+reg)=m
#pragma unroll
  for (int j = 0; j < 2; ++j) {
    const int n = n0 + wn + j * 16 + lr;
    if (n < N) {
      const float bz = bias[n];
#pragma unroll
      for (int i = 0; i < 4; ++i) {
        const int mb = m0 + wm + i * 16 + lc * 4;
#pragma unroll
        for (int r = 0; r < 4; ++r)
          C[(size_t)(mb + r) * (size_t)ldc + n] =
              accM[i][j][r] + 0.00048828125f * accL[i][j][r] + bz;
      }
    }
  }
}

// ---------- 1b) encoder post: ReLU+LN16+router+nsc + gi tail planes ----------
__global__ __launch_bounds__(256) void enc_post(
    const float* __restrict__ mfraw,
    const float* __restrict__ vol_g, const float* __restrict__ vol_bb,
    const float* __restrict__ trend_g, const float* __restrict__ trend_bb,
    const float* __restrict__ mom_g, const float* __restrict__ mom_bb,
    const float* __restrict__ reg_g, const float* __restrict__ reg_bb,
    const float* __restrict__ rc1_w, const float* __restrict__ rc1_b,
    const float* __restrict__ rc2_w, const float* __restrict__ rc2_b,
    const float* __restrict__ ns1_w, const float* __restrict__ ns1_b,
    const float* __restrict__ ns2_w, const float* __restrict__ ns2_b,
    float* __restrict__ rp4, float* __restrict__ nsc,
    unsigned short* __restrict__ gip) {
  __shared__ float smf[16][64];
  __shared__ float shid[16][32];
  __shared__ float srp[16][4];
  const int t = threadIdx.x, w = t >> 6, e = t & 63;
  const int br = e >> 4;
  const int rowbase0 = blockIdx.x * 16;

  const float* gsel = (br == 0) ? vol_g : (br == 1) ? trend_g : (br == 2) ? mom_g : reg_g;
  const float* bbsel = (br == 0) ? vol_bb : (br == 1) ? trend_bb : (br == 2) ? mom_bb : reg_bb;
  const float gv = gsel[e & 15];
  const float bbv = bbsel[e & 15];
#pragma unroll
  for (int r = 0; r < 4; ++r) {
    const int row = w * 4 + r;
    const float raw = mfraw[(size_t)(rowbase0 + row) * 64 + e];
    const float v = fmaxf(raw, 0.f);
    const float mu = gsum16(v) * (1.f / 16.f);
    const float d = v - mu;
    const float var = gsum16(d * d) * (1.f / 16.f);
    smf[row][e] = d * (1.f / sqrtf(var + 1e-5f)) * gv + bbv;
  }
  __syncthreads();

  if (e < 32) {
#pragma unroll
    for (int r = 0; r < 4; ++r) {
      const int row = w * 4 + r;
      float h = rc1_b[e];
#pragma unroll 8
      for (int j = 0; j < 64; ++j) h += rc1_w[e * 64 + j] * smf[row][j];
      shid[row][e] = fmaxf(h, 0.f);
    }
  }
  __syncthreads();
  if (e < 16) {
    const int r = e >> 2, l = e & 3;
    const int row = w * 4 + r;
    float z = rc2_b[l];
#pragma unroll 8
    for (int j = 0; j < 32; ++j) z += rc2_w[l * 32 + j] * shid[row][j];
    float mx = z;
    mx = fmaxf(mx, __shfl_xor(mx, 1));
    mx = fmaxf(mx, __shfl_xor(mx, 2));
    const float ex = expf(z - mx);
    float s = ex;
    s += __shfl_xor(s, 1);
    s += __shfl_xor(s, 2);
    const float rp = ex / s;
    srp[row][l] = rp;
    rp4[(size_t)(rowbase0 + row) * 4 + l] = rp;
  }
  __syncthreads();
  if (e < 4) {
    const int row = w * 4 + e;
    const float rp0 = srp[row][0], rp1 = srp[row][1], rp2 = srp[row][2], rp3 = srp[row][3];
    float z = ns2_b[0];
#pragma unroll
    for (int i = 0; i < 16; ++i) {
      float h = ns1_b[i] + ns1_w[i * 4 + 0] * rp0 + ns1_w[i * 4 + 1] * rp1 +
                ns1_w[i * 4 + 2] * rp2 + ns1_w[i * 4 + 3] * rp3;
      z += ns2_w[i] * fmaxf(h, 0.f);
    }
    nsc[rowbase0 + row] = 1.f / (1.f + expf(-z));
  }
  __syncthreads();
  // gi tail planes (kt 16..19): 16 rows x 16 items = 256 -> one per thread
  {
    const int rib = t >> 4;
    const int item = t & 15;
    const int kt = 16 + (item >> 2), c = item & 3;
    const int kbase = kt * 32 + c * 8;
    const size_t grow = (size_t)rowbase0 + rib;
    float v[8];
#pragma unroll
    for (int s = 0; s < 8; ++s) {
      const int k = kbase + s;
      float f = 0.f;
      if (k < 576) f = smf[rib][k - 512];
      else if (k < 580) f = srp[rib][k - 576];
      v[s] = f;
    }
    write_chunks(gip, grow, 20, kt, c, v);
  }
}

// ---------- 2) tail v3: 8 rows/block, k-split GEMV with shared Wt pass ----------
__global__ __launch_bounds__(256) void tail_v3(
    const float* __restrict__ Zraw, const float* __restrict__ gamma,
    const float* __restrict__ beta, const float* __restrict__ Wt,
    const float* __restrict__ bias,
    const float* __restrict__ rp4, const float* __restrict__ nsc,
    const float* __restrict__ noise, const float* __restrict__ spec,
    float* __restrict__ out, float* __restrict__ pg, float* __restrict__ pl) {
  __shared__ __align__(16) float arowT[580][12];
  __shared__ float spart[4][8][64];
  __shared__ float sgp[4][64], slp[4][64];
  const int t = threadIdx.x, w = t >> 6, e = t & 63;

  // ph1: LN + GELU for this wave's 2 rows
#pragma unroll
  for (int rr = 0; rr < 2; ++rr) {
    const int r = w * 2 + rr;
    const int row = blockIdx.x * 8 + r;
    const float* zr = Zraw + (size_t)row * 580;
    float vals[10];
    float s = 0.f, ss = 0.f;
#pragma unroll
    for (int c = 0; c < 10; ++c) {
      const int k = e + c * 64;
      const float v = (k < 580) ? zr[k] : 0.f;
      vals[c] = v;
      s += v;
      ss += v * v;
    }
    s = wsum64(s);
    ss = wsum64(ss);
    const float mu = s * (1.f / 580.f);
    const float var = fmaxf(ss * (1.f / 580.f) - mu * mu, 0.f);
    const float rs = 1.f / sqrtf(var + 1e-5f);
#pragma unroll
    for (int c = 0; c < 10; ++c) {
      const int k = e + c * 64;
      if (k < 580)
        arowT[k][r] = gelu_exact((vals[c] - mu) * rs * gamma[k] + beta[k]);
    }
  }
  __syncthreads();

  // ph2: k-split GEMV
  float part[8] = {};
  const int k0 = w * 145;
#pragma unroll 4
  for (int kk = 0; kk < 145; ++kk) {
    const int k = k0 + kk;
    const float4 a0 = *(const float4*)&arowT[k][0];
    const float4 a1 = *(const float4*)&arowT[k][4];
    const float wv = Wt[k * 64 + e];
    part[0] = fmaf(a0.x, wv, part[0]);
    part[1] = fmaf(a0.y, wv, part[1]);
    part[2] = fmaf(a0.z, wv, part[2]);
    part[3] = fmaf(a0.w, wv, part[3]);
    part[4] = fmaf(a1.x, wv, part[4]);
    part[5] = fmaf(a1.y, wv, part[5]);
    part[6] = fmaf(a1.z, wv, part[6]);
    part[7] = fmaf(a1.w, wv, part[7]);
  }
#pragma unroll
  for (int r = 0; r < 8; ++r) spart[w][r][e] = part[r];
  __syncthreads();

  // ph3: finish this wave's 2 rows
  const float4 sp = *(const float4*)(spec + e * 4);
  const float bz = bias[e];
  float accg = 0.f, accl = 0.f;
#pragma unroll
  for (int rr = 0; rr < 2; ++rr) {
    const int r = w * 2 + rr;
    const int row = blockIdx.x * 8 + r;
    float c = bz + ((spart[0][r][e] + spart[1][r][e]) + (spart[2][r][e] + spart[3][r][e]));
    const float4 rp = *(const float4*)(rp4 + (size_t)row * 4);
    c += rp.x * sp.x + rp.y * sp.y + rp.z * sp.z + rp.w * sp.w;
    const float nv = noise[(size_t)row * 64 + e];
    const float noisy = c + nv * nsc[row];
    float v = noisy;
    int ix = e;
#pragma unroll
    for (int off = 32; off; off >>= 1) {
      const float ov = __shfl_xor(v, off);
      const int oi = __shfl_xor(ix, off);
      if (ov > v || (ov == v && oi < ix)) { v = ov; ix = oi; }
    }
    const float v1 = v;
    const int i1 = ix;
    float v2 = (e == i1) ? -FLT_MAX : noisy;
    int ix2 = e;
#pragma unroll
    for (int off = 32; off; off >>= 1) {
      const float ov = __shfl_xor(v2, off);
      const int oi = __shfl_xor(ix2, off);
      if (ov > v2 || (ov == v2 && oi < ix2)) { v2 = ov; ix2 = oi; }
    }
    const int i2 = ix2;
    if (e == 0) {
      const float texp = expf(v2 - v1);
      const float tw0 = 1.f / (1.f + texp);
      out[(size_t)row * 2 + 0] = tw0;
      out[(size_t)row * 2 + 1] = texp * tw0;
      out[32768 + (size_t)row * 2 + 0] = (float)i1;
      out[32768 + (size_t)row * 2 + 1] = (float)i2;
    }
    const float mx = wmax64(c);
    const float p = expf(c - mx);
    const float ssum = wsum64(p);
    accg += p / ssum;
    accl += (e == i1 || e == i2) ? 1.f : 0.f;
  }
  sgp[w][e] = accg;
  slp[w][e] = accl;
  __syncthreads();
  if (t < 64) {
    pg[blockIdx.x * 64 + t] = sgp[0][t] + sgp[1][t] + sgp[2][t] + sgp[3][t];
    pl[blockIdx.x * 64 + t] = slp[0][t] + slp[1][t] + slp[2][t] + slp[3][t];
  }
}

// ---------- 3) ln_gelu_split v4: register-resident, no LDS, no barriers ----------
__global__ __launch_bounds__(256) void ln_gelu_split_v4(
    const float* __restrict__ Z, const float* __restrict__ gamma,
    const float* __restrict__ beta, unsigned short* __restrict__ P) {
  const int N = 1160, KT = 38;
  const int t = threadIdx.x, w = t >> 6, l = t & 63;
  const size_t row = (size_t)blockIdx.x * 4 + w;
  const float* zr = Z + row * N;
  float vals[3][8];
  float s = 0.f;
#pragma unroll
  for (int c = 0; c < 3; ++c) {
    const int ch = l + c * 64;
    if (ch < 145) {
      const float4 u0 = *(const float4*)(zr + ch * 8);
      const float4 u1 = *(const float4*)(zr + ch * 8 + 4);
      vals[c][0] = u0.x; vals[c][1] = u0.y; vals[c][2] = u0.z; vals[c][3] = u0.w;
      vals[c][4] = u1.x; vals[c][5] = u1.y; vals[c][6] = u1.z; vals[c][7] = u1.w;
      s += ((u0.x + u0.y) + (u0.z + u0.w)) + ((u1.x + u1.y) + (u1.z + u1.w));
    } else {
#pragma unroll
      for (int k = 0; k < 8; ++k) vals[c][k] = 0.f;
    }
  }
  s = wsum64(s);
  const float mu = s * (1.f / 1160.f);
  float q = 0.f;
#pragma unroll
  for (int c = 0; c < 3; ++c) {
    const int ch = l + c * 64;
    if (ch < 145) {
#pragma unroll
      for (int k = 0; k < 8; ++k) {
        const float d = vals[c][k] - mu;
        q += d * d;
      }
    }
  }
  q = wsum64(q);
  const float rstd = 1.f / sqrtf(q * (1.f / 1160.f) + 1e-5f);
#pragma unroll
  for (int c = 0; c < 3; ++c) {
    const int ch = l + c * 64;
    if (ch < 152) {
      float g[8];
      if (ch < 145) {
        const int kb = ch * 8;
#pragma unroll
        for (int k = 0; k < 8; ++k)
          g[k] = gelu_exact((vals[c][k] - mu) * rstd * gamma[kb + k] + beta[kb + k]);
      } else {
#pragma unroll
        for (int k = 0; k < 8; ++k) g[k] = 0.f;
      }
      write_chunks(P, row, KT, ch >> 2, ch & 3, g);
    }
  }
}

// ---------- 5) aux loss (hierarchical over 2048 block-partials) ----------
__global__ __launch_bounds__(1024) void loss_kernel2(
    const float* __restrict__ pg, const float* __restrict__ pl,
    float* __restrict__ out) {
  __shared__ float sgl[16][64], sll[16][64];
  const int t = threadIdx.x, w = t >> 6, e = t & 63;
  float g = 0.f, l = 0.f;
  for (int b = w; b < 2048; b += 16) {
    g += pg[b * 64 + e];
    l += pl[b * 64 + e];
  }
  sgl[w][e] = g;
  sll[w][e] = l;
  __syncthreads();
  if (t < 64) {
    float gg = 0.f, ll = 0.f;
#pragma unroll
    for (int i = 0; i < 16; ++i) { gg += sgl[i][t]; ll += sll[i][t]; }
    const float prob = gg * (1.f / 16384.f);
    const float ld = ll * (1.f / 16384.f);
    const float load_loss = 64.f * wsum64(prob * ld);
    const float sgs = wsum64(gg);
    const float mean = sgs * (1.f / 64.f);
    const float d = gg - mean;
    const float var = wsum64(d * d) * (1.f / 63.f);
    if (t == 0) out[65536] = 0.01f * load_loss + 0.01f * (var / mean);
  }
}

extern "C" void kernel_launch(void* const* d_in, const int* in_sizes, int n_in,
                              void* d_out, int out_size, void* d_ws, size_t ws_size,
                              hipStream_t stream) {
  (void)in_sizes; (void)n_in; (void)out_size; (void)ws_size;
  const float* x = (const float*)d_in[0];
  const float* noise = (const float*)d_in[1];
  const float* vol_w = (const float*)d_in[2];
  const float* vol_b = (const float*)d_in[3];
  const float* vol_g = (const float*)d_in[4];
  const float* vol_bb = (const float*)d_in[5];
  const float* trend_w = (const float*)d_in[6];
  const float* trend_b = (const float*)d_in[7];
  const float* trend_g = (const float*)d_in[8];
  const float* trend_bb = (const float*)d_in[9];
  const float* mom_w = (const float*)d_in[10];
  const float* mom_b = (const float*)d_in[11];
  const float* mom_g = (const float*)d_in[12];
  const float* mom_bb = (const float*)d_in[13];
  const float* reg_w = (const float*)d_in[14];
  const float* reg_b = (const float*)d_in[15];
  const float* reg_g = (const float*)d_in[16];
  const float* reg_bb = (const float*)d_in[17];
  const float* rc1_w = (const float*)d_in[18];
  const float* rc1_b = (const float*)d_in[19];
  const float* rc2_w = (const float*)d_in[20];
  const float* rc2_b = (const float*)d_in[21];
  const float* g1_w = (const float*)d_in[22];
  const float* g1_b = (const float*)d_in[23];
  const float* g1_g = (const float*)d_in[24];
  const float* g1_bb = (const float*)d_in[25];
  const float* g2_w = (const float*)d_in[26];
  const float* g2_b = (const float*)d_in[27];
  const float* g2_g = (const float*)d_in[28];
  const float* g2_bb = (const float*)d_in[29];
  const float* g3_w = (const float*)d_in[30];
  const float* g3_b = (const float*)d_in[31];
  const float* ns1_w = (const float*)d_in[32];
  const float* ns1_b = (const float*)d_in[33];
  const float* ns2_w = (const float*)d_in[34];
  const float* ns2_b = (const float*)d_in[35];
  const float* spec = (const float*)d_in[36];
  float* out = (float*)d_out;

  const size_t B = BROWS;
  float* ws = (float*)d_ws;
  float* rp4 = ws;                                    // B*4 f32
  float* nsc = rp4 + B * 4;                           // B f32
  float* z1 = nsc + B;                                // B*1160 f32
  unsigned short* gip = (unsigned short*)(z1 + B * 1160);  // B*1280 ush (KT=20)
  float* z2 = (float*)gip;                            // alias: B*580 f32 (gi dead after G1)
  unsigned short* z1p = gip + B * 1280;               // B*2432 ush (KT=38)
  unsigned short* w1p = z1p + B * 2432;               // 1280*1280 ush
  unsigned short* w2p = w1p + (size_t)1280 * 1280;    // 640*2432 ush
  unsigned short* wencp = w2p + (size_t)640 * 2432;   // 128*1024 ush
  float* wt = (float*)(wencp + 128 * 1024);           // 580*64 f32
  float* benc = wt + 580 * 64;                        // 64 f32
  float* pg = benc + 64;                              // 2048*64
  float* pl = pg + 2048 * 64;                         // 2048*64
  float* mfraw = pl + 2048 * 64;                      // B*64 f32

  hipFuncSetAttribute(reinterpret_cast<const void*>(gemm_fp16x3_v8),
                      hipFuncAttributeMaxDynamicSharedMemorySize, 65536);

  // prep: all splits + transposes (one launch)
  prep_kernel<<<5054, 256, 0, stream>>>(
      x, g1_w, w1p, g2_w, w2p, vol_w, trend_w, mom_w, reg_w, wencp,
      g3_w, wt, vol_b, trend_b, mom_b, reg_b, benc, gip);

  // encoder GEMM: [16384,512] x [64,512]^T -> mfraw ; A=gip (strideA 1280, KT=16)
  gemm_fp16x3_v8<<<128, 512, 65536, stream>>>(
      gip, wencp, benc, mfraw, 64, 16, 64, 1, 1280, 1024);

  // encoder post: ReLU+LN16+router+nsc + gi tail planes
  enc_post<<<1024, 256, 0, stream>>>(
      mfraw, vol_g, vol_bb, trend_g, trend_bb, mom_g, mom_bb, reg_g, reg_bb,
      rc1_w, rc1_b, rc2_w, rc2_b, ns1_w, ns1_b, ns2_w, ns2_b, rp4, nsc, gip);

  // G1: [16384,640] x [1280,640]^T -> z1
  gemm_fp16x3_v8<<<1280, 512, 65536, stream>>>(
      gip, w1p, g1_b, z1, 1160, 20, 1160, 10, 1280, 1280);
  ln_gelu_split_v4<<<4096, 256, 0, stream>>>(z1, g1_g, g1_bb, z1p);

  // G2: [16384,1216] x [640,1216]^T -> z2
  gemm_fp16x3_v8<<<640, 512, 65536, stream>>>(
      z1p, w2p, g2_b, z2, 580, 38, 580, 5, 2432, 2432);

  // tail: LN+GELU+G3-GEMV+noisy-top2+partials (8 rows/block, shared Wt pass)
  tail_v3<<<2048, 256, 0, stream>>>(
      z2, g2_g, g2_bb, wt, g3_b, rp4, nsc, noise, spec, out, pg, pl);
  loss_kernel2<<<1, 1024, 0, stream>>>(pg, pl, out);
}

// Round 19
// 354.385 us; speedup vs baseline: 1.1390x; 1.0083x over previous
//
#include <hip/hip_runtime.h>
#include <hip/hip_fp16.h>
#include <cfloat>

#define BROWS 16384

typedef float f32x4 __attribute__((ext_vector_type(4)));
typedef _Float16 f16x8 __attribute__((ext_vector_type(8)));

// ---------- wave helpers ----------
__device__ __forceinline__ float wsum64(float v) {
#pragma unroll
  for (int off = 32; off; off >>= 1) v += __shfl_xor(v, off);
  return v;
}
__device__ __forceinline__ float wmax64(float v) {
#pragma unroll
  for (int off = 32; off; off >>= 1) v = fmaxf(v, __shfl_xor(v, off));
  return v;
}
__device__ __forceinline__ float gsum16(float v) {
#pragma unroll
  for (int off = 1; off < 16; off <<= 1) v += __shfl_xor(v, off);
  return v;
}

// exact-GELU via branchless A&S 7.1.26 erf (max abs err 1.5e-7 ~ fp32 noise)
__device__ __forceinline__ float gelu_exact(float y) {
  const float x = y * 0.70710678118654752f;
  const float ax = fabsf(x);
  const float t = 1.f / fmaf(0.3275911f, ax, 1.f);
  float p = fmaf(1.061405429f, t, -1.453152027f);
  p = fmaf(p, t, 1.421413741f);
  p = fmaf(p, t, -0.284496736f);
  p = fmaf(p, t, 0.254829592f);
  p = p * t;
  const float e = __expf(-ax * ax);
  const float er = fmaf(-p, e, 1.f);
  const float erfx = copysignf(er, x);
  return 0.5f * y * (1.f + erfx);
}

// fp16 2-limb split: v ~= h0 + 2^-11 * h1, residual <= 2^-24 |v|
__device__ __forceinline__ void split2(float v, unsigned short& o0, unsigned short& o1) {
  const _Float16 h0 = (_Float16)v;
  const float r = (v - (float)h0) * 2048.0f;
  const _Float16 h1 = (_Float16)r;
  o0 = __builtin_bit_cast(unsigned short, h0);
  o1 = __builtin_bit_cast(unsigned short, h1);
}

// async global -> LDS, 16B per lane, dest = wave-uniform base + lane*16
__device__ __forceinline__ void gll16(const unsigned short* g, unsigned short* l) {
  __builtin_amdgcn_global_load_lds(
      (const __attribute__((address_space(1))) unsigned int*)g,
      (__attribute__((address_space(3))) unsigned int*)l, 16, 0, 0);
}

// Combined swizzled plane format (2 fp16 limbs):
//   buf[(r*KT + kt)*64 + p*8 + s], physical chunk p = c ^ (r&7);
//   c 0..3 = limb0, c 4..7 = limb1. Conflict-free ds_read_b128.
__device__ __forceinline__ void write_chunks(
    unsigned short* __restrict__ P, size_t row, int KT, int kt, int c,
    const float* vals8) {
  unsigned short h0[8], h1[8];
#pragma unroll
  for (int s = 0; s < 8; ++s) split2(vals8[s], h0[s], h1[s]);
  const int r7 = (int)(row & 7);
  const size_t o = ((size_t)row * KT + kt) * 64;
  *(uint4*)&P[o + (size_t)((c ^ r7) * 8)] = *(const uint4*)h0;
  *(uint4*)&P[o + (size_t)(((4 + c) ^ r7) * 8)] = *(const uint4*)h1;
}

// ---------- 0) prep: all weight/x splits in one launch ----------
__device__ __forceinline__ void split_w_body(
    const float* __restrict__ W, unsigned short* __restrict__ P,
    unsigned idx, int Nreal, int Kreal, int KT) {
  const unsigned ipr = (unsigned)(KT * 4);
  const unsigned row = idx / ipr;
  const unsigned item = idx - row * ipr;
  const int kt = item >> 2, c = item & 3;
  float v[8];
#pragma unroll
  for (int s = 0; s < 8; ++s) {
    const int k = kt * 32 + c * 8 + s;
    v[s] = ((int)row < Nreal && k < Kreal) ? W[(size_t)row * Kreal + k] : 0.f;
  }
  write_chunks(P, row, KT, kt, c, v);
}

__global__ __launch_bounds__(256) void prep_kernel(
    const float* __restrict__ x,
    const float* __restrict__ W1, unsigned short* __restrict__ P1,
    const float* __restrict__ W2, unsigned short* __restrict__ P2,
    const float* __restrict__ vol_w, const float* __restrict__ trend_w,
    const float* __restrict__ mom_w, const float* __restrict__ reg_w,
    unsigned short* __restrict__ Pe,
    const float* __restrict__ W3, float* __restrict__ Wt,
    const float* __restrict__ vol_b, const float* __restrict__ trend_b,
    const float* __restrict__ mom_b, const float* __restrict__ reg_b,
    float* __restrict__ benc,
    unsigned short* __restrict__ gip) {
  const unsigned bid = blockIdx.x;
  const int t = threadIdx.x;
  if (bid < 400) {        // W1: Npad=1280, KT=20
    split_w_body(W1, P1, bid * 256 + t, 1160, 580, 20);
  } else if (bid < 780) { // W2: Npad=640, KT=38
    split_w_body(W2, P2, (bid - 400) * 256 + t, 580, 1160, 38);
  } else if (bid < 812) { // Wenc: Npad=128, KT=16
    const unsigned idx = (bid - 780) * 256 + t;  // < 8192 = 128*64
    const unsigned row = idx >> 6;
    const unsigned item = idx & 63;
    const int kt = (int)(item >> 2), c = (int)(item & 3);
    float v[8];
    const float* wsrc = nullptr;
    if (row < 64) {
      const int br = (int)(row >> 4);
      wsrc = (br == 0) ? vol_w : (br == 1) ? trend_w : (br == 2) ? mom_w : reg_w;
      wsrc += (size_t)(row & 15) * 512;
    }
#pragma unroll
    for (int s = 0; s < 8; ++s) {
      const int k = kt * 32 + c * 8 + s;
      v[s] = wsrc ? wsrc[k] : 0.f;
    }
    write_chunks(Pe, row, 16, kt, c, v);
  } else if (bid < 957) { // W3 transpose: Wt[k][n] = W3[n][k], 580x64
    const unsigned idx = (bid - 812) * 256 + t;  // < 37120
    const unsigned k = idx >> 6, n = idx & 63;
    Wt[k * 64 + n] = W3[(size_t)n * 580 + k];
  } else if (bid == 957) { // benc: concat branch biases
    if (t < 64) {
      const int br = t >> 4;
      const float* bsel = (br == 0) ? vol_b : (br == 1) ? trend_b : (br == 2) ? mom_b : reg_b;
      benc[t] = bsel[t & 15];
    }
  } else {                // x -> gi planes kt 0..15
    const unsigned idx = (bid - 958) * 256 + t;  // < 16384*64
    const unsigned row = idx >> 6;
    const unsigned item = idx & 63;
    const int kt = (int)(item >> 2), c = (int)(item & 3);
    const int kbase = kt * 32 + c * 8;
    float v[8];
    const float4 u0 = *(const float4*)(x + (size_t)row * 512 + kbase);
    const float4 u1 = *(const float4*)(x + (size_t)row * 512 + kbase + 4);
    v[0] = u0.x; v[1] = u0.y; v[2] = u0.z; v[3] = u0.w;
    v[4] = u1.x; v[5] = u1.y; v[6] = u1.z; v[7] = u1.w;
    write_chunks(gip, row, 20, kt, c, v);
  }
}

// ---------- 1) fp16x3 MFMA GEMM v9: 4 waves, 64x64/wave (3:1 MFMA:ds_read) ----------
// v8's proven 2-slot/d=1/pinned ring, but 256 threads as 2x2 waves, each wave
// owning a 64x64 quadrant: 48 MFMA + 16 ds_read_b128 per iteration (vs v8's
// 24+12) -> LDS-read pipe (v8's binding pipe by arithmetic) drops below MFMA.
// LDS 64KB -> 2 blocks/CU preserved (m114 overlap). 8 gll16/wave/stage ->
// steady s_waitcnt vmcnt(8).
__global__ __launch_bounds__(256, 2) void gemm_fp16x3_v9(
    const unsigned short* __restrict__ Ap, const unsigned short* __restrict__ Bp,
    const float* __restrict__ bias, float* __restrict__ C,
    int N, int KT, int ldc, int nbx, int strideA, int strideB) {
  extern __shared__ __align__(16) unsigned short smem[];  // 2 * 16384 ushorts
  const int t = threadIdx.x;
  const int wg = (blockIdx.x & 7) * ((int)gridDim.x >> 3) + (blockIdx.x >> 3);
  const int bx = wg % nbx, by = wg / nbx;
  const int m0 = by * 128, n0 = bx * 128;
  const int w = t >> 6, l = t & 63;
  const int lr = l & 15, lc = l >> 4;
  const int wm = (w >> 1) * 64, wn = (w & 1) * 64;

  // staging: wave w covers A rows w*32..w*32+31 and B rows likewise
  size_t aoff[4], boff[4];
#pragma unroll
  for (int c = 0; c < 4; ++c) {
    const int rb = w * 32 + c * 8;
    aoff[c] = (size_t)(m0 + rb + (l >> 3)) * (size_t)strideA + (size_t)((l & 7) * 8);
    boff[c] = (size_t)(n0 + rb + (l >> 3)) * (size_t)strideB + (size_t)((l & 7) * 8);
  }

  f32x4 accM[4][4], accL[4][4];
#pragma unroll
  for (int i = 0; i < 4; ++i)
#pragma unroll
    for (int j = 0; j < 4; ++j) {
      accM[i][j] = (f32x4){0.f, 0.f, 0.f, 0.f};
      accL[i][j] = (f32x4){0.f, 0.f, 0.f, 0.f};
    }

  auto stage = [&](int kt, int slot) {
    unsigned short* base = smem + slot * 16384;
    const size_t ko = (size_t)kt * 64;
#pragma unroll
    for (int c = 0; c < 4; ++c) {
      const int rb = w * 32 + c * 8;
      gll16(Ap + aoff[c] + ko, base + rb * 64);
      gll16(Bp + boff[c] + ko, base + 8192 + rb * 64);
    }
  };

  stage(0, 0);
  __builtin_amdgcn_sched_barrier(0);
  int cur = 0;
  for (int kt = 0; kt < KT; ++kt) {
    __builtin_amdgcn_sched_barrier(0);
    if (kt + 1 < KT) {
      stage(kt + 1, cur ^ 1);               // writes the OTHER slot
      __builtin_amdgcn_sched_barrier(0);    // pin: stage issued before the count
      asm volatile("s_waitcnt vmcnt(8)" ::: "memory");  // stage(kt) landed
    } else {
      asm volatile("s_waitcnt vmcnt(0)" ::: "memory");
    }
    __builtin_amdgcn_sched_barrier(0);
    __builtin_amdgcn_s_barrier();           // all waves' stage(kt) visible
    __builtin_amdgcn_sched_barrier(0);

    const unsigned short* base = smem + cur * 16384;
    f16x8 a0[4], a1[4], b0[4], b1[4];
#pragma unroll
    for (int i = 0; i < 4; ++i) {
      const int ar = wm + i * 16 + lr;
      const int r7 = ar & 7;
      a0[i] = *(const f16x8*)&base[ar * 64 + ((lc ^ r7) << 3)];
      a1[i] = *(const f16x8*)&base[ar * 64 + (((4 + lc) ^ r7) << 3)];
    }
#pragma unroll
    for (int j = 0; j < 4; ++j) {
      const int brj = wn + j * 16 + lr;
      const int r7 = brj & 7;
      b0[j] = *(const f16x8*)&base[8192 + brj * 64 + ((lc ^ r7) << 3)];
      b1[j] = *(const f16x8*)&base[8192 + brj * 64 + (((4 + lc) ^ r7) << 3)];
    }
    __builtin_amdgcn_s_setprio(1);
#pragma unroll
    for (int i = 0; i < 4; ++i)
#pragma unroll
      for (int j = 0; j < 4; ++j)
        accM[i][j] = __builtin_amdgcn_mfma_f32_16x16x32_f16(a0[i], b0[j], accM[i][j], 0, 0, 0);
#pragma unroll
    for (int i = 0; i < 4; ++i)
#pragma unroll
      for (int j = 0; j < 4; ++j)
        accL[i][j] = __builtin_amdgcn_mfma_f32_16x16x32_f16(a1[i], b0[j], accL[i][j], 0, 0, 0);
#pragma unroll
    for (int i = 0; i < 4; ++i)
#pragma unroll
      for (int j = 0; j < 4; ++j)
        accL[i][j] = __builtin_amdgcn_mfma_f32_16x16x32_f16(a0[i], b1[j], accL[i][j], 0, 0, 0);
    __builtin_amdgcn_s_setprio(0);
    __builtin_amdgcn_sched_barrier(0);
    __builtin_amdgcn_s_barrier();           // WAR: all done reading cur
    __builtin_amdgcn_sched_barrier(0);      // pin: next iter's stage stays below
    cur ^= 1;
  }
  // epilogue: D layout col(lane&15)=n, row((lane>>4)*4+reg)=m
#pragma unroll
  for (int j = 0; j < 4; ++j) {
    const int n = n0 + wn + j * 16 + lr;
    if (n < N) {
      const float bz = bias[n];
#pragma unroll
      for (int i = 0; i < 4; ++i) {
        const int mb = m0 + wm + i * 16 + lc * 4;
#pragma unroll
        for (int r = 0; r < 4; ++r)
          C[(size_t)(mb + r) * (size_t)ldc + n] =
              accM[i][j][r] + 0.00048828125f * accL[i][j][r] + bz;
      }
    }
  }
}

// ---------- 1b) encoder post: ReLU+LN16+router+nsc + gi tail planes ----------
__global__ __launch_bounds__(256) void enc_post(
    const float* __restrict__ mfraw,
    const float* __restrict__ vol_g, const float* __restrict__ vol_bb,
    const float* __restrict__ trend_g, const float* __restrict__ trend_bb,
    const float* __restrict__ mom_g, const float* __restrict__ mom_bb,
    const float* __restrict__ reg_g, const float* __restrict__ reg_bb,
    const float* __restrict__ rc1_w, const float* __restrict__ rc1_b,
    const float* __restrict__ rc2_w, const float* __restrict__ rc2_b,
    const float* __restrict__ ns1_w, const float* __restrict__ ns1_b,
    const float* __restrict__ ns2_w, const float* __restrict__ ns2_b,
    float* __restrict__ rp4, float* __restrict__ nsc,
    unsigned short* __restrict__ gip) {
  __shared__ float smf[16][64];
  __shared__ float shid[16][32];
  __shared__ float srp[16][4];
  const int t = threadIdx.x, w = t >> 6, e = t & 63;
  const int br = e >> 4;
  const int rowbase0 = blockIdx.x * 16;

  const float* gsel = (br == 0) ? vol_g : (br == 1) ? trend_g : (br == 2) ? mom_g : reg_g;
  const float* bbsel = (br == 0) ? vol_bb : (br == 1) ? trend_bb : (br == 2) ? mom_bb : reg_bb;
  const float gv = gsel[e & 15];
  const float bbv = bbsel[e & 15];
#pragma unroll
  for (int r = 0; r < 4; ++r) {
    const int row = w * 4 + r;
    const float raw = mfraw[(size_t)(rowbase0 + row) * 64 + e];
    const float v = fmaxf(raw, 0.f);
    const float mu = gsum16(v) * (1.f / 16.f);
    const float d = v - mu;
    const float var = gsum16(d * d) * (1.f / 16.f);
    smf[row][e] = d * (1.f / sqrtf(var + 1e-5f)) * gv + bbv;
  }
  __syncthreads();

  if (e < 32) {
#pragma unroll
    for (int r = 0; r < 4; ++r) {
      const int row = w * 4 + r;
      float h = rc1_b[e];
#pragma unroll 8
      for (int j = 0; j < 64; ++j) h += rc1_w[e * 64 + j] * smf[row][j];
      shid[row][e] = fmaxf(h, 0.f);
    }
  }
  __syncthreads();
  if (e < 16) {
    const int r = e >> 2, l = e & 3;
    const int row = w * 4 + r;
    float z = rc2_b[l];
#pragma unroll 8
    for (int j = 0; j < 32; ++j) z += rc2_w[l * 32 + j] * shid[row][j];
    float mx = z;
    mx = fmaxf(mx, __shfl_xor(mx, 1));
    mx = fmaxf(mx, __shfl_xor(mx, 2));
    const float ex = expf(z - mx);
    float s = ex;
    s += __shfl_xor(s, 1);
    s += __shfl_xor(s, 2);
    const float rp = ex / s;
    srp[row][l] = rp;
    rp4[(size_t)(rowbase0 + row) * 4 + l] = rp;
  }
  __syncthreads();
  if (e < 4) {
    const int row = w * 4 + e;
    const float rp0 = srp[row][0], rp1 = srp[row][1], rp2 = srp[row][2], rp3 = srp[row][3];
    float z = ns2_b[0];
#pragma unroll
    for (int i = 0; i < 16; ++i) {
      float h = ns1_b[i] + ns1_w[i * 4 + 0] * rp0 + ns1_w[i * 4 + 1] * rp1 +
                ns1_w[i * 4 + 2] * rp2 + ns1_w[i * 4 + 3] * rp3;
      z += ns2_w[i] * fmaxf(h, 0.f);
    }
    nsc[rowbase0 + row] = 1.f / (1.f + expf(-z));
  }
  __syncthreads();
  // gi tail planes (kt 16..19): 16 rows x 16 items = 256 -> one per thread
  {
    const int rib = t >> 4;
    const int item = t & 15;
    const int kt = 16 + (item >> 2), c = item & 3;
    const int kbase = kt * 32 + c * 8;
    const size_t grow = (size_t)rowbase0 + rib;
    float v[8];
#pragma unroll
    for (int s = 0; s < 8; ++s) {
      const int k = kbase + s;
      float f = 0.f;
      if (k < 576) f = smf[rib][k - 512];
      else if (k < 580) f = srp[rib][k - 576];
      v[s] = f;
    }
    write_chunks(gip, grow, 20, kt, c, v);
  }
}

// ---------- 2) tail v3: 8 rows/block, k-split GEMV with shared Wt pass ----------
__global__ __launch_bounds__(256) void tail_v3(
    const float* __restrict__ Zraw, const float* __restrict__ gamma,
    const float* __restrict__ beta, const float* __restrict__ Wt,
    const float* __restrict__ bias,
    const float* __restrict__ rp4, const float* __restrict__ nsc,
    const float* __restrict__ noise, const float* __restrict__ spec,
    float* __restrict__ out, float* __restrict__ pg, float* __restrict__ pl) {
  __shared__ __align__(16) float arowT[580][12];
  __shared__ float spart[4][8][64];
  __shared__ float sgp[4][64], slp[4][64];
  const int t = threadIdx.x, w = t >> 6, e = t & 63;

  // ph1: LN + GELU for this wave's 2 rows
#pragma unroll
  for (int rr = 0; rr < 2; ++rr) {
    const int r = w * 2 + rr;
    const int row = blockIdx.x * 8 + r;
    const float* zr = Zraw + (size_t)row * 580;
    float vals[10];
    float s = 0.f, ss = 0.f;
#pragma unroll
    for (int c = 0; c < 10; ++c) {
      const int k = e + c * 64;
      const float v = (k < 580) ? zr[k] : 0.f;
      vals[c] = v;
      s += v;
      ss += v * v;
    }
    s = wsum64(s);
    ss = wsum64(ss);
    const float mu = s * (1.f / 580.f);
    const float var = fmaxf(ss * (1.f / 580.f) - mu * mu, 0.f);
    const float rs = 1.f / sqrtf(var + 1e-5f);
#pragma unroll
    for (int c = 0; c < 10; ++c) {
      const int k = e + c * 64;
      if (k < 580)
        arowT[k][r] = gelu_exact((vals[c] - mu) * rs * gamma[k] + beta[k]);
    }
  }
  __syncthreads();

  // ph2: k-split GEMV
  float part[8] = {};
  const int k0 = w * 145;
#pragma unroll 4
  for (int kk = 0; kk < 145; ++kk) {
    const int k = k0 + kk;
    const float4 a0 = *(const float4*)&arowT[k][0];
    const float4 a1 = *(const float4*)&arowT[k][4];
    const float wv = Wt[k * 64 + e];
    part[0] = fmaf(a0.x, wv, part[0]);
    part[1] = fmaf(a0.y, wv, part[1]);
    part[2] = fmaf(a0.z, wv, part[2]);
    part[3] = fmaf(a0.w, wv, part[3]);
    part[4] = fmaf(a1.x, wv, part[4]);
    part[5] = fmaf(a1.y, wv, part[5]);
    part[6] = fmaf(a1.z, wv, part[6]);
    part[7] = fmaf(a1.w, wv, part[7]);
  }
#pragma unroll
  for (int r = 0; r < 8; ++r) spart[w][r][e] = part[r];
  __syncthreads();

  // ph3: finish this wave's 2 rows
  const float4 sp = *(const float4*)(spec + e * 4);
  const float bz = bias[e];
  float accg = 0.f, accl = 0.f;
#pragma unroll
  for (int rr = 0; rr < 2; ++rr) {
    const int r = w * 2 + rr;
    const int row = blockIdx.x * 8 + r;
    float c = bz + ((spart[0][r][e] + spart[1][r][e]) + (spart[2][r][e] + spart[3][r][e]));
    const float4 rp = *(const float4*)(rp4 + (size_t)row * 4);
    c += rp.x * sp.x + rp.y * sp.y + rp.z * sp.z + rp.w * sp.w;
    const float nv = noise[(size_t)row * 64 + e];
    const float noisy = c + nv * nsc[row];
    float v = noisy;
    int ix = e;
#pragma unroll
    for (int off = 32; off; off >>= 1) {
      const float ov = __shfl_xor(v, off);
      const int oi = __shfl_xor(ix, off);
      if (ov > v || (ov == v && oi < ix)) { v = ov; ix = oi; }
    }
    const float v1 = v;
    const int i1 = ix;
    float v2 = (e == i1) ? -FLT_MAX : noisy;
    int ix2 = e;
#pragma unroll
    for (int off = 32; off; off >>= 1) {
      const float ov = __shfl_xor(v2, off);
      const int oi = __shfl_xor(ix2, off);
      if (ov > v2 || (ov == v2 && oi < ix2)) { v2 = ov; ix2 = oi; }
    }
    const int i2 = ix2;
    if (e == 0) {
      const float texp = expf(v2 - v1);
      const float tw0 = 1.f / (1.f + texp);
      out[(size_t)row * 2 + 0] = tw0;
      out[(size_t)row * 2 + 1] = texp * tw0;
      out[32768 + (size_t)row * 2 + 0] = (float)i1;
      out[32768 + (size_t)row * 2 + 1] = (float)i2;
    }
    const float mx = wmax64(c);
    const float p = expf(c - mx);
    const float ssum = wsum64(p);
    accg += p / ssum;
    accl += (e == i1 || e == i2) ? 1.f : 0.f;
  }
  sgp[w][e] = accg;
  slp[w][e] = accl;
  __syncthreads();
  if (t < 64) {
    pg[blockIdx.x * 64 + t] = sgp[0][t] + sgp[1][t] + sgp[2][t] + sgp[3][t];
    pl[blockIdx.x * 64 + t] = slp[0][t] + slp[1][t] + slp[2][t] + slp[3][t];
  }
}

// ---------- 3) ln_gelu_split v4: register-resident, no LDS, no barriers ----------
__global__ __launch_bounds__(256) void ln_gelu_split_v4(
    const float* __restrict__ Z, const float* __restrict__ gamma,
    const float* __restrict__ beta, unsigned short* __restrict__ P) {
  const int N = 1160, KT = 38;
  const int t = threadIdx.x, w = t >> 6, l = t & 63;
  const size_t row = (size_t)blockIdx.x * 4 + w;
  const float* zr = Z + row * N;
  float vals[3][8];
  float s = 0.f;
#pragma unroll
  for (int c = 0; c < 3; ++c) {
    const int ch = l + c * 64;
    if (ch < 145) {
      const float4 u0 = *(const float4*)(zr + ch * 8);
      const float4 u1 = *(const float4*)(zr + ch * 8 + 4);
      vals[c][0] = u0.x; vals[c][1] = u0.y; vals[c][2] = u0.z; vals[c][3] = u0.w;
      vals[c][4] = u1.x; vals[c][5] = u1.y; vals[c][6] = u1.z; vals[c][7] = u1.w;
      s += ((u0.x + u0.y) + (u0.z + u0.w)) + ((u1.x + u1.y) + (u1.z + u1.w));
    } else {
#pragma unroll
      for (int k = 0; k < 8; ++k) vals[c][k] = 0.f;
    }
  }
  s = wsum64(s);
  const float mu = s * (1.f / 1160.f);
  float q = 0.f;
#pragma unroll
  for (int c = 0; c < 3; ++c) {
    const int ch = l + c * 64;
    if (ch < 145) {
#pragma unroll
      for (int k = 0; k < 8; ++k) {
        const float d = vals[c][k] - mu;
        q += d * d;
      }
    }
  }
  q = wsum64(q);
  const float rstd = 1.f / sqrtf(q * (1.f / 1160.f) + 1e-5f);
#pragma unroll
  for (int c = 0; c < 3; ++c) {
    const int ch = l + c * 64;
    if (ch < 152) {
      float g[8];
      if (ch < 145) {
        const int kb = ch * 8;
#pragma unroll
        for (int k = 0; k < 8; ++k)
          g[k] = gelu_exact((vals[c][k] - mu) * rstd * gamma[kb + k] + beta[kb + k]);
      } else {
#pragma unroll
        for (int k = 0; k < 8; ++k) g[k] = 0.f;
      }
      write_chunks(P, row, KT, ch >> 2, ch & 3, g);
    }
  }
}

// ---------- 5) aux loss (hierarchical over 2048 block-partials) ----------
__global__ __launch_bounds__(1024) void loss_kernel2(
    const float* __restrict__ pg, const float* __restrict__ pl,
    float* __restrict__ out) {
  __shared__ float sgl[16][64], sll[16][64];
  const int t = threadIdx.x, w = t >> 6, e = t & 63;
  float g = 0.f, l = 0.f;
  for (int b = w; b < 2048; b += 16) {
    g += pg[b * 64 + e];
    l += pl[b * 64 + e];
  }
  sgl[w][e] = g;
  sll[w][e] = l;
  __syncthreads();
  if (t < 64) {
    float gg = 0.f, ll = 0.f;
#pragma unroll
    for (int i = 0; i < 16; ++i) { gg += sgl[i][t]; ll += sll[i][t]; }
    const float prob = gg * (1.f / 16384.f);
    const float ld = ll * (1.f / 16384.f);
    const float load_loss = 64.f * wsum64(prob * ld);
    const float sgs = wsum64(gg);
    const float mean = sgs * (1.f / 64.f);
    const float d = gg - mean;
    const float var = wsum64(d * d) * (1.f / 63.f);
    if (t == 0) out[65536] = 0.01f * load_loss + 0.01f * (var / mean);
  }
}

extern "C" void kernel_launch(void* const* d_in, const int* in_sizes, int n_in,
                              void* d_out, int out_size, void* d_ws, size_t ws_size,
                              hipStream_t stream) {
  (void)in_sizes; (void)n_in; (void)out_size; (void)ws_size;
  const float* x = (const float*)d_in[0];
  const float* noise = (const float*)d_in[1];
  const float* vol_w = (const float*)d_in[2];
  const float* vol_b = (const float*)d_in[3];
  const float* vol_g = (const float*)d_in[4];
  const float* vol_bb = (const float*)d_in[5];
  const float* trend_w = (const float*)d_in[6];
  const float* trend_b = (const float*)d_in[7];
  const float* trend_g = (const float*)d_in[8];
  const float* trend_bb = (const float*)d_in[9];
  const float* mom_w = (const float*)d_in[10];
  const float* mom_b = (const float*)d_in[11];
  const float* mom_g = (const float*)d_in[12];
  const float* mom_bb = (const float*)d_in[13];
  const float* reg_w = (const float*)d_in[14];
  const float* reg_b = (const float*)d_in[15];
  const float* reg_g = (const float*)d_in[16];
  const float* reg_bb = (const float*)d_in[17];
  const float* rc1_w = (const float*)d_in[18];
  const float* rc1_b = (const float*)d_in[19];
  const float* rc2_w = (const float*)d_in[20];
  const float* rc2_b = (const float*)d_in[21];
  const float* g1_w = (const float*)d_in[22];
  const float* g1_b = (const float*)d_in[23];
  const float* g1_g = (const float*)d_in[24];
  const float* g1_bb = (const float*)d_in[25];
  const float* g2_w = (const float*)d_in[26];
  const float* g2_b = (const float*)d_in[27];
  const float* g2_g = (const float*)d_in[28];
  const float* g2_bb = (const float*)d_in[29];
  const float* g3_w = (const float*)d_in[30];
  const float* g3_b = (const float*)d_in[31];
  const float* ns1_w = (const float*)d_in[32];
  const float* ns1_b = (const float*)d_in[33];
  const float* ns2_w = (const float*)d_in[34];
  const float* ns2_b = (const float*)d_in[35];
  const float* spec = (const float*)d_in[36];
  float* out = (float*)d_out;

  const size_t B = BROWS;
  float* ws = (float*)d_ws;
  float* rp4 = ws;                                    // B*4 f32
  float* nsc = rp4 + B * 4;                           // B f32
  float* z1 = nsc + B;                                // B*1160 f32
  unsigned short* gip = (unsigned short*)(z1 + B * 1160);  // B*1280 ush (KT=20)
  float* z2 = (float*)gip;                            // alias: B*580 f32 (gi dead after G1)
  unsigned short* z1p = gip + B * 1280;               // B*2432 ush (KT=38)
  unsigned short* w1p = z1p + B * 2432;               // 1280*1280 ush
  unsigned short* w2p = w1p + (size_t)1280 * 1280;    // 640*2432 ush
  unsigned short* wencp = w2p + (size_t)640 * 2432;   // 128*1024 ush
  float* wt = (float*)(wencp + 128 * 1024);           // 580*64 f32
  float* benc = wt + 580 * 64;                        // 64 f32
  float* pg = benc + 64;                              // 2048*64
  float* pl = pg + 2048 * 64;                         // 2048*64
  float* mfraw = pl + 2048 * 64;                      // B*64 f32

  hipFuncSetAttribute(reinterpret_cast<const void*>(gemm_fp16x3_v9),
                      hipFuncAttributeMaxDynamicSharedMemorySize, 65536);

  // prep: all splits + transposes (one launch)
  prep_kernel<<<5054, 256, 0, stream>>>(
      x, g1_w, w1p, g2_w, w2p, vol_w, trend_w, mom_w, reg_w, wencp,
      g3_w, wt, vol_b, trend_b, mom_b, reg_b, benc, gip);

  // encoder GEMM: [16384,512] x [64,512]^T -> mfraw ; A=gip (strideA 1280, KT=16)
  gemm_fp16x3_v9<<<128, 256, 65536, stream>>>(
      gip, wencp, benc, mfraw, 64, 16, 64, 1, 1280, 1024);

  // encoder post: ReLU+LN16+router+nsc + gi tail planes
  enc_post<<<1024, 256, 0, stream>>>(
      mfraw, vol_g, vol_bb, trend_g, trend_bb, mom_g, mom_bb, reg_g, reg_bb,
      rc1_w, rc1_b, rc2_w, rc2_b, ns1_w, ns1_b, ns2_w, ns2_b, rp4, nsc, gip);

  // G1: [16384,640] x [1280,640]^T -> z1
  gemm_fp16x3_v9<<<1280, 256, 65536, stream>>>(
      gip, w1p, g1_b, z1, 1160, 20, 1160, 10, 1280, 1280);
  ln_gelu_split_v4<<<4096, 256, 0, stream>>>(z1, g1_g, g1_bb, z1p);

  // G2: [16384,1216] x [640,1216]^T -> z2
  gemm_fp16x3_v9<<<640, 256, 65536, stream>>>(
      z1p, w2p, g2_b, z2, 580, 38, 580, 5, 2432, 2432);

  // tail: LN+GELU+G3-GEMV+noisy-top2+partials (8 rows/block, shared Wt pass)
  tail_v3<<<2048, 256, 0, stream>>>(
      z2, g2_g, g2_bb, wt, g3_b, rp4, nsc, noise, spec, out, pg, pl);
  loss_kernel2<<<1, 1024, 0, stream>>>(pg, pl, out);
}

// Round 20
// 345.957 us; speedup vs baseline: 1.1667x; 1.0244x over previous
//
#include <hip/hip_runtime.h>
#include <hip/hip_fp16.h>
#include <cfloat>

#define BROWS 16384

typedef float f32x4 __attribute__((ext_vector_type(4)));
typedef _Float16 f16x8 __attribute__((ext_vector_type(8)));

// ---------- wave helpers ----------
__device__ __forceinline__ float wsum64(float v) {
#pragma unroll
  for (int off = 32; off; off >>= 1) v += __shfl_xor(v, off);
  return v;
}
__device__ __forceinline__ float wmax64(float v) {
#pragma unroll
  for (int off = 32; off; off >>= 1) v = fmaxf(v, __shfl_xor(v, off));
  return v;
}
__device__ __forceinline__ float gsum16(float v) {
#pragma unroll
  for (int off = 1; off < 16; off <<= 1) v += __shfl_xor(v, off);
  return v;
}

// exact-GELU via branchless A&S 7.1.26 erf (max abs err 1.5e-7 ~ fp32 noise)
__device__ __forceinline__ float gelu_exact(float y) {
  const float x = y * 0.70710678118654752f;
  const float ax = fabsf(x);
  const float t = 1.f / fmaf(0.3275911f, ax, 1.f);
  float p = fmaf(1.061405429f, t, -1.453152027f);
  p = fmaf(p, t, 1.421413741f);
  p = fmaf(p, t, -0.284496736f);
  p = fmaf(p, t, 0.254829592f);
  p = p * t;
  const float e = __expf(-ax * ax);
  const float er = fmaf(-p, e, 1.f);
  const float erfx = copysignf(er, x);
  return 0.5f * y * (1.f + erfx);
}

// fp16 2-limb split: v ~= h0 + 2^-11 * h1, residual <= 2^-24 |v|
__device__ __forceinline__ void split2(float v, unsigned short& o0, unsigned short& o1) {
  const _Float16 h0 = (_Float16)v;
  const float r = (v - (float)h0) * 2048.0f;
  const _Float16 h1 = (_Float16)r;
  o0 = __builtin_bit_cast(unsigned short, h0);
  o1 = __builtin_bit_cast(unsigned short, h1);
}

// async global -> LDS, 16B per lane, dest = wave-uniform base + lane*16
__device__ __forceinline__ void gll16(const unsigned short* g, unsigned short* l) {
  __builtin_amdgcn_global_load_lds(
      (const __attribute__((address_space(1))) unsigned int*)g,
      (__attribute__((address_space(3))) unsigned int*)l, 16, 0, 0);
}

// Combined swizzled plane format (2 fp16 limbs):
//   buf[(r*KT + kt)*64 + p*8 + s], physical chunk p = c ^ (r&7);
//   c 0..3 = limb0, c 4..7 = limb1. Conflict-free ds_read_b128.
__device__ __forceinline__ void write_chunks(
    unsigned short* __restrict__ P, size_t row, int KT, int kt, int c,
    const float* vals8) {
  unsigned short h0[8], h1[8];
#pragma unroll
  for (int s = 0; s < 8; ++s) split2(vals8[s], h0[s], h1[s]);
  const int r7 = (int)(row & 7);
  const size_t o = ((size_t)row * KT + kt) * 64;
  *(uint4*)&P[o + (size_t)((c ^ r7) * 8)] = *(const uint4*)h0;
  *(uint4*)&P[o + (size_t)(((4 + c) ^ r7) * 8)] = *(const uint4*)h1;
}

// ---------- 0) prep: all weight/x splits in one launch ----------
__device__ __forceinline__ void split_w_body(
    const float* __restrict__ W, unsigned short* __restrict__ P,
    unsigned idx, int Nreal, int Kreal, int KT) {
  const unsigned ipr = (unsigned)(KT * 4);
  const unsigned row = idx / ipr;
  const unsigned item = idx - row * ipr;
  const int kt = item >> 2, c = item & 3;
  float v[8];
#pragma unroll
  for (int s = 0; s < 8; ++s) {
    const int k = kt * 32 + c * 8 + s;
    v[s] = ((int)row < Nreal && k < Kreal) ? W[(size_t)row * Kreal + k] : 0.f;
  }
  write_chunks(P, row, KT, kt, c, v);
}

__global__ __launch_bounds__(256) void prep_kernel(
    const float* __restrict__ x,
    const float* __restrict__ W1, unsigned short* __restrict__ P1,
    const float* __restrict__ W2, unsigned short* __restrict__ P2,
    const float* __restrict__ vol_w, const float* __restrict__ trend_w,
    const float* __restrict__ mom_w, const float* __restrict__ reg_w,
    unsigned short* __restrict__ Pe,
    const float* __restrict__ W3, float* __restrict__ Wt,
    const float* __restrict__ vol_b, const float* __restrict__ trend_b,
    const float* __restrict__ mom_b, const float* __restrict__ reg_b,
    float* __restrict__ benc,
    unsigned short* __restrict__ gip) {
  const unsigned bid = blockIdx.x;
  const int t = threadIdx.x;
  if (bid < 400) {        // W1: Npad=1280, KT=20
    split_w_body(W1, P1, bid * 256 + t, 1160, 580, 20);
  } else if (bid < 780) { // W2: Npad=640, KT=38
    split_w_body(W2, P2, (bid - 400) * 256 + t, 580, 1160, 38);
  } else if (bid < 812) { // Wenc: Npad=128, KT=16
    const unsigned idx = (bid - 780) * 256 + t;  // < 8192 = 128*64
    const unsigned row = idx >> 6;
    const unsigned item = idx & 63;
    const int kt = (int)(item >> 2), c = (int)(item & 3);
    float v[8];
    const float* wsrc = nullptr;
    if (row < 64) {
      const int br = (int)(row >> 4);
      wsrc = (br == 0) ? vol_w : (br == 1) ? trend_w : (br == 2) ? mom_w : reg_w;
      wsrc += (size_t)(row & 15) * 512;
    }
#pragma unroll
    for (int s = 0; s < 8; ++s) {
      const int k = kt * 32 + c * 8 + s;
      v[s] = wsrc ? wsrc[k] : 0.f;
    }
    write_chunks(Pe, row, 16, kt, c, v);
  } else if (bid < 957) { // W3 transpose: Wt[k][n] = W3[n][k], 580x64
    const unsigned idx = (bid - 812) * 256 + t;  // < 37120
    const unsigned k = idx >> 6, n = idx & 63;
    Wt[k * 64 + n] = W3[(size_t)n * 580 + k];
  } else if (bid == 957) { // benc: concat branch biases
    if (t < 64) {
      const int br = t >> 4;
      const float* bsel = (br == 0) ? vol_b : (br == 1) ? trend_b : (br == 2) ? mom_b : reg_b;
      benc[t] = bsel[t & 15];
    }
  } else {                // x -> gi planes kt 0..15
    const unsigned idx = (bid - 958) * 256 + t;  // < 16384*64
    const unsigned row = idx >> 6;
    const unsigned item = idx & 63;
    const int kt = (int)(item >> 2), c = (int)(item & 3);
    const int kbase = kt * 32 + c * 8;
    float v[8];
    const float4 u0 = *(const float4*)(x + (size_t)row * 512 + kbase);
    const float4 u1 = *(const float4*)(x + (size_t)row * 512 + kbase + 4);
    v[0] = u0.x; v[1] = u0.y; v[2] = u0.z; v[3] = u0.w;
    v[4] = u1.x; v[5] = u1.y; v[6] = u1.z; v[7] = u1.w;
    write_chunks(gip, row, 20, kt, c, v);
  }
}

// ---------- 1) fp16x3 MFMA GEMM v10: 128x64 tile, 48KB LDS -> 3 blocks/CU ----------
// Occupancy experiment: v8/v9 measured ~1 block/CU resident (Occupancy 12-24%),
// so the designed cross-block overlap never happened. Slot = A 16KB + B 8KB =
// 24KB; 2 slots = 48KB -> 3 blocks/CU by LDS (12 waves). 4 waves as 2M x 2N,
// per-wave 64x32 output: 24 MFMA + 12 ds_read_b128 per iter. Same pinned
// d=1 ring as v8 (proven race-free discipline); 6 gll16/wave -> vmcnt(6).
__global__ __launch_bounds__(256, 3) void gemm_fp16x3_v10(
    const unsigned short* __restrict__ Ap, const unsigned short* __restrict__ Bp,
    const float* __restrict__ bias, float* __restrict__ C,
    int N, int KT, int ldc, int nbx, int strideA, int strideB) {
  extern __shared__ __align__(16) unsigned short smem[];  // 2 * 12288 ushorts
  const int t = threadIdx.x;
  const int wg = (blockIdx.x & 7) * ((int)gridDim.x >> 3) + (blockIdx.x >> 3);
  const int bx = wg % nbx, by = wg / nbx;
  const int m0 = by * 128, n0 = bx * 64;
  const int w = t >> 6, l = t & 63;
  const int lr = l & 15, lc = l >> 4;
  const int wm = (w >> 1) * 64, wn = (w & 1) * 32;

  // staging: wave w covers A rows w*32..w*32+31 (4 calls) + B rows w*16..+15 (2 calls)
  size_t aoff[4], boff[2];
#pragma unroll
  for (int c = 0; c < 4; ++c) {
    const int rb = w * 32 + c * 8;
    aoff[c] = (size_t)(m0 + rb + (l >> 3)) * (size_t)strideA + (size_t)((l & 7) * 8);
  }
#pragma unroll
  for (int c = 0; c < 2; ++c) {
    const int rb = w * 16 + c * 8;
    boff[c] = (size_t)(n0 + rb + (l >> 3)) * (size_t)strideB + (size_t)((l & 7) * 8);
  }

  f32x4 accM[4][2], accL[4][2];
#pragma unroll
  for (int i = 0; i < 4; ++i)
#pragma unroll
    for (int j = 0; j < 2; ++j) {
      accM[i][j] = (f32x4){0.f, 0.f, 0.f, 0.f};
      accL[i][j] = (f32x4){0.f, 0.f, 0.f, 0.f};
    }

  auto stage = [&](int kt, int slot) {
    unsigned short* base = smem + slot * 12288;
    const size_t ko = (size_t)kt * 64;
#pragma unroll
    for (int c = 0; c < 4; ++c)
      gll16(Ap + aoff[c] + ko, base + (w * 32 + c * 8) * 64);
#pragma unroll
    for (int c = 0; c < 2; ++c)
      gll16(Bp + boff[c] + ko, base + 8192 + (w * 16 + c * 8) * 64);
  };

  stage(0, 0);
  __builtin_amdgcn_sched_barrier(0);
  int cur = 0;
  for (int kt = 0; kt < KT; ++kt) {
    __builtin_amdgcn_sched_barrier(0);
    if (kt + 1 < KT) {
      stage(kt + 1, cur ^ 1);               // writes the OTHER slot
      __builtin_amdgcn_sched_barrier(0);    // pin: stage issued before the count
      asm volatile("s_waitcnt vmcnt(6)" ::: "memory");  // stage(kt) landed
    } else {
      asm volatile("s_waitcnt vmcnt(0)" ::: "memory");
    }
    __builtin_amdgcn_sched_barrier(0);
    __builtin_amdgcn_s_barrier();           // all waves' stage(kt) visible
    __builtin_amdgcn_sched_barrier(0);

    const unsigned short* base = smem + cur * 12288;
    f16x8 a0[4], a1[4], b0[2], b1[2];
#pragma unroll
    for (int i = 0; i < 4; ++i) {
      const int ar = wm + i * 16 + lr;
      const int r7 = ar & 7;
      a0[i] = *(const f16x8*)&base[ar * 64 + ((lc ^ r7) << 3)];
      a1[i] = *(const f16x8*)&base[ar * 64 + (((4 + lc) ^ r7) << 3)];
    }
#pragma unroll
    for (int j = 0; j < 2; ++j) {
      const int brj = wn + j * 16 + lr;
      const int r7 = brj & 7;
      b0[j] = *(const f16x8*)&base[8192 + brj * 64 + ((lc ^ r7) << 3)];
      b1[j] = *(const f16x8*)&base[8192 + brj * 64 + (((4 + lc) ^ r7) << 3)];
    }
    __builtin_amdgcn_s_setprio(1);
#pragma unroll
    for (int i = 0; i < 4; ++i)
#pragma unroll
      for (int j = 0; j < 2; ++j)
        accM[i][j] = __builtin_amdgcn_mfma_f32_16x16x32_f16(a0[i], b0[j], accM[i][j], 0, 0, 0);
#pragma unroll
    for (int i = 0; i < 4; ++i)
#pragma unroll
      for (int j = 0; j < 2; ++j)
        accL[i][j] = __builtin_amdgcn_mfma_f32_16x16x32_f16(a1[i], b0[j], accL[i][j], 0, 0, 0);
#pragma unroll
    for (int i = 0; i < 4; ++i)
#pragma unroll
      for (int j = 0; j < 2; ++j)
        accL[i][j] = __builtin_amdgcn_mfma_f32_16x16x32_f16(a0[i], b1[j], accL[i][j], 0, 0, 0);
    __builtin_amdgcn_s_setprio(0);
    __builtin_amdgcn_sched_barrier(0);
    __builtin_amdgcn_s_barrier();           // WAR: all done reading cur
    __builtin_amdgcn_sched_barrier(0);      // pin: next iter's stage stays below
    cur ^= 1;
  }
  // epilogue: D layout col(lane&15)=n, row((lane>>4)*4+reg)=m
#pragma unroll
  for (int j = 0; j < 2; ++j) {
    const int n = n0 + wn + j * 16 + lr;
    if (n < N) {
      const float bz = bias[n];
#pragma unroll
      for (int i = 0; i < 4; ++i) {
        const int mb = m0 + wm + i * 16 + lc * 4;
#pragma unroll
        for (int r = 0; r < 4; ++r)
          C[(size_t)(mb + r) * (size_t)ldc + n] =
              accM[i][j][r] + 0.00048828125f * accL[i][j][r] + bz;
      }
    }
  }
}

// ---------- 1b) encoder post: ReLU+LN16+router+nsc + gi tail planes ----------
__global__ __launch_bounds__(256) void enc_post(
    const float* __restrict__ mfraw,
    const float* __restrict__ vol_g, const float* __restrict__ vol_bb,
    const float* __restrict__ trend_g, const float* __restrict__ trend_bb,
    const float* __restrict__ mom_g, const float* __restrict__ mom_bb,
    const float* __restrict__ reg_g, const float* __restrict__ reg_bb,
    const float* __restrict__ rc1_w, const float* __restrict__ rc1_b,
    const float* __restrict__ rc2_w, const float* __restrict__ rc2_b,
    const float* __restrict__ ns1_w, const float* __restrict__ ns1_b,
    const float* __restrict__ ns2_w, const float* __restrict__ ns2_b,
    float* __restrict__ rp4, float* __restrict__ nsc,
    unsigned short* __restrict__ gip) {
  __shared__ float smf[16][64];
  __shared__ float shid[16][32];
  __shared__ float srp[16][4];
  const int t = threadIdx.x, w = t >> 6, e = t & 63;
  const int br = e >> 4;
  const int rowbase0 = blockIdx.x * 16;

  const float* gsel = (br == 0) ? vol_g : (br == 1) ? trend_g : (br == 2) ? mom_g : reg_g;
  const float* bbsel = (br == 0) ? vol_bb : (br == 1) ? trend_bb : (br == 2) ? mom_bb : reg_bb;
  const float gv = gsel[e & 15];
  const float bbv = bbsel[e & 15];
#pragma unroll
  for (int r = 0; r < 4; ++r) {
    const int row = w * 4 + r;
    const float raw = mfraw[(size_t)(rowbase0 + row) * 64 + e];
    const float v = fmaxf(raw, 0.f);
    const float mu = gsum16(v) * (1.f / 16.f);
    const float d = v - mu;
    const float var = gsum16(d * d) * (1.f / 16.f);
    smf[row][e] = d * (1.f / sqrtf(var + 1e-5f)) * gv + bbv;
  }
  __syncthreads();

  if (e < 32) {
#pragma unroll
    for (int r = 0; r < 4; ++r) {
      const int row = w * 4 + r;
      float h = rc1_b[e];
#pragma unroll 8
      for (int j = 0; j < 64; ++j) h += rc1_w[e * 64 + j] * smf[row][j];
      shid[row][e] = fmaxf(h, 0.f);
    }
  }
  __syncthreads();
  if (e < 16) {
    const int r = e >> 2, l = e & 3;
    const int row = w * 4 + r;
    float z = rc2_b[l];
#pragma unroll 8
    for (int j = 0; j < 32; ++j) z += rc2_w[l * 32 + j] * shid[row][j];
    float mx = z;
    mx = fmaxf(mx, __shfl_xor(mx, 1));
    mx = fmaxf(mx, __shfl_xor(mx, 2));
    const float ex = expf(z - mx);
    float s = ex;
    s += __shfl_xor(s, 1);
    s += __shfl_xor(s, 2);
    const float rp = ex / s;
    srp[row][l] = rp;
    rp4[(size_t)(rowbase0 + row) * 4 + l] = rp;
  }
  __syncthreads();
  if (e < 4) {
    const int row = w * 4 + e;
    const float rp0 = srp[row][0], rp1 = srp[row][1], rp2 = srp[row][2], rp3 = srp[row][3];
    float z = ns2_b[0];
#pragma unroll
    for (int i = 0; i < 16; ++i) {
      float h = ns1_b[i] + ns1_w[i * 4 + 0] * rp0 + ns1_w[i * 4 + 1] * rp1 +
                ns1_w[i * 4 + 2] * rp2 + ns1_w[i * 4 + 3] * rp3;
      z += ns2_w[i] * fmaxf(h, 0.f);
    }
    nsc[rowbase0 + row] = 1.f / (1.f + expf(-z));
  }
  __syncthreads();
  // gi tail planes (kt 16..19): 16 rows x 16 items = 256 -> one per thread
  {
    const int rib = t >> 4;
    const int item = t & 15;
    const int kt = 16 + (item >> 2), c = item & 3;
    const int kbase = kt * 32 + c * 8;
    const size_t grow = (size_t)rowbase0 + rib;
    float v[8];
#pragma unroll
    for (int s = 0; s < 8; ++s) {
      const int k = kbase + s;
      float f = 0.f;
      if (k < 576) f = smf[rib][k - 512];
      else if (k < 580) f = srp[rib][k - 576];
      v[s] = f;
    }
    write_chunks(gip, grow, 20, kt, c, v);
  }
}

// ---------- 2) tail v3: 8 rows/block, k-split GEMV with shared Wt pass ----------
__global__ __launch_bounds__(256) void tail_v3(
    const float* __restrict__ Zraw, const float* __restrict__ gamma,
    const float* __restrict__ beta, const float* __restrict__ Wt,
    const float* __restrict__ bias,
    const float* __restrict__ rp4, const float* __restrict__ nsc,
    const float* __restrict__ noise, const float* __restrict__ spec,
    float* __restrict__ out, float* __restrict__ pg, float* __restrict__ pl) {
  __shared__ __align__(16) float arowT[580][12];
  __shared__ float spart[4][8][64];
  __shared__ float sgp[4][64], slp[4][64];
  const int t = threadIdx.x, w = t >> 6, e = t & 63;

  // ph1: LN + GELU for this wave's 2 rows
#pragma unroll
  for (int rr = 0; rr < 2; ++rr) {
    const int r = w * 2 + rr;
    const int row = blockIdx.x * 8 + r;
    const float* zr = Zraw + (size_t)row * 580;
    float vals[10];
    float s = 0.f, ss = 0.f;
#pragma unroll
    for (int c = 0; c < 10; ++c) {
      const int k = e + c * 64;
      const float v = (k < 580) ? zr[k] : 0.f;
      vals[c] = v;
      s += v;
      ss += v * v;
    }
    s = wsum64(s);
    ss = wsum64(ss);
    const float mu = s * (1.f / 580.f);
    const float var = fmaxf(ss * (1.f / 580.f) - mu * mu, 0.f);
    const float rs = 1.f / sqrtf(var + 1e-5f);
#pragma unroll
    for (int c = 0; c < 10; ++c) {
      const int k = e + c * 64;
      if (k < 580)
        arowT[k][r] = gelu_exact((vals[c] - mu) * rs * gamma[k] + beta[k]);
    }
  }
  __syncthreads();

  // ph2: k-split GEMV
  float part[8] = {};
  const int k0 = w * 145;
#pragma unroll 4
  for (int kk = 0; kk < 145; ++kk) {
    const int k = k0 + kk;
    const float4 a0 = *(const float4*)&arowT[k][0];
    const float4 a1 = *(const float4*)&arowT[k][4];
    const float wv = Wt[k * 64 + e];
    part[0] = fmaf(a0.x, wv, part[0]);
    part[1] = fmaf(a0.y, wv, part[1]);
    part[2] = fmaf(a0.z, wv, part[2]);
    part[3] = fmaf(a0.w, wv, part[3]);
    part[4] = fmaf(a1.x, wv, part[4]);
    part[5] = fmaf(a1.y, wv, part[5]);
    part[6] = fmaf(a1.z, wv, part[6]);
    part[7] = fmaf(a1.w, wv, part[7]);
  }
#pragma unroll
  for (int r = 0; r < 8; ++r) spart[w][r][e] = part[r];
  __syncthreads();

  // ph3: finish this wave's 2 rows
  const float4 sp = *(const float4*)(spec + e * 4);
  const float bz = bias[e];
  float accg = 0.f, accl = 0.f;
#pragma unroll
  for (int rr = 0; rr < 2; ++rr) {
    const int r = w * 2 + rr;
    const int row = blockIdx.x * 8 + r;
    float c = bz + ((spart[0][r][e] + spart[1][r][e]) + (spart[2][r][e] + spart[3][r][e]));
    const float4 rp = *(const float4*)(rp4 + (size_t)row * 4);
    c += rp.x * sp.x + rp.y * sp.y + rp.z * sp.z + rp.w * sp.w;
    const float nv = noise[(size_t)row * 64 + e];
    const float noisy = c + nv * nsc[row];
    float v = noisy;
    int ix = e;
#pragma unroll
    for (int off = 32; off; off >>= 1) {
      const float ov = __shfl_xor(v, off);
      const int oi = __shfl_xor(ix, off);
      if (ov > v || (ov == v && oi < ix)) { v = ov; ix = oi; }
    }
    const float v1 = v;
    const int i1 = ix;
    float v2 = (e == i1) ? -FLT_MAX : noisy;
    int ix2 = e;
#pragma unroll
    for (int off = 32; off; off >>= 1) {
      const float ov = __shfl_xor(v2, off);
      const int oi = __shfl_xor(ix2, off);
      if (ov > v2 || (ov == v2 && oi < ix2)) { v2 = ov; ix2 = oi; }
    }
    const int i2 = ix2;
    if (e == 0) {
      const float texp = expf(v2 - v1);
      const float tw0 = 1.f / (1.f + texp);
      out[(size_t)row * 2 + 0] = tw0;
      out[(size_t)row * 2 + 1] = texp * tw0;
      out[32768 + (size_t)row * 2 + 0] = (float)i1;
      out[32768 + (size_t)row * 2 + 1] = (float)i2;
    }
    const float mx = wmax64(c);
    const float p = expf(c - mx);
    const float ssum = wsum64(p);
    accg += p / ssum;
    accl += (e == i1 || e == i2) ? 1.f : 0.f;
  }
  sgp[w][e] = accg;
  slp[w][e] = accl;
  __syncthreads();
  if (t < 64) {
    pg[blockIdx.x * 64 + t] = sgp[0][t] + sgp[1][t] + sgp[2][t] + sgp[3][t];
    pl[blockIdx.x * 64 + t] = slp[0][t] + slp[1][t] + slp[2][t] + slp[3][t];
  }
}

// ---------- 3) ln_gelu_split v4: register-resident, no LDS, no barriers ----------
__global__ __launch_bounds__(256) void ln_gelu_split_v4(
    const float* __restrict__ Z, const float* __restrict__ gamma,
    const float* __restrict__ beta, unsigned short* __restrict__ P) {
  const int N = 1160, KT = 38;
  const int t = threadIdx.x, w = t >> 6, l = t & 63;
  const size_t row = (size_t)blockIdx.x * 4 + w;
  const float* zr = Z + row * N;
  float vals[3][8];
  float s = 0.f;
#pragma unroll
  for (int c = 0; c < 3; ++c) {
    const int ch = l + c * 64;
    if (ch < 145) {
      const float4 u0 = *(const float4*)(zr + ch * 8);
      const float4 u1 = *(const float4*)(zr + ch * 8 + 4);
      vals[c][0] = u0.x; vals[c][1] = u0.y; vals[c][2] = u0.z; vals[c][3] = u0.w;
      vals[c][4] = u1.x; vals[c][5] = u1.y; vals[c][6] = u1.z; vals[c][7] = u1.w;
      s += ((u0.x + u0.y) + (u0.z + u0.w)) + ((u1.x + u1.y) + (u1.z + u1.w));
    } else {
#pragma unroll
      for (int k = 0; k < 8; ++k) vals[c][k] = 0.f;
    }
  }
  s = wsum64(s);
  const float mu = s * (1.f / 1160.f);
  float q = 0.f;
#pragma unroll
  for (int c = 0; c < 3; ++c) {
    const int ch = l + c * 64;
    if (ch < 145) {
#pragma unroll
      for (int k = 0; k < 8; ++k) {
        const float d = vals[c][k] - mu;
        q += d * d;
      }
    }
  }
  q = wsum64(q);
  const float rstd = 1.f / sqrtf(q * (1.f / 1160.f) + 1e-5f);
#pragma unroll
  for (int c = 0; c < 3; ++c) {
    const int ch = l + c * 64;
    if (ch < 152) {
      float g[8];
      if (ch < 145) {
        const int kb = ch * 8;
#pragma unroll
        for (int k = 0; k < 8; ++k)
          g[k] = gelu_exact((vals[c][k] - mu) * rstd * gamma[kb + k] + beta[kb + k]);
      } else {
#pragma unroll
        for (int k = 0; k < 8; ++k) g[k] = 0.f;
      }
      write_chunks(P, row, KT, ch >> 2, ch & 3, g);
    }
  }
}

// ---------- 5) aux loss (hierarchical over 2048 block-partials) ----------
__global__ __launch_bounds__(1024) void loss_kernel2(
    const float* __restrict__ pg, const float* __restrict__ pl,
    float* __restrict__ out) {
  __shared__ float sgl[16][64], sll[16][64];
  const int t = threadIdx.x, w = t >> 6, e = t & 63;
  float g = 0.f, l = 0.f;
  for (int b = w; b < 2048; b += 16) {
    g += pg[b * 64 + e];
    l += pl[b * 64 + e];
  }
  sgl[w][e] = g;
  sll[w][e] = l;
  __syncthreads();
  if (t < 64) {
    float gg = 0.f, ll = 0.f;
#pragma unroll
    for (int i = 0; i < 16; ++i) { gg += sgl[i][t]; ll += sll[i][t]; }
    const float prob = gg * (1.f / 16384.f);
    const float ld = ll * (1.f / 16384.f);
    const float load_loss = 64.f * wsum64(prob * ld);
    const float sgs = wsum64(gg);
    const float mean = sgs * (1.f / 64.f);
    const float d = gg - mean;
    const float var = wsum64(d * d) * (1.f / 63.f);
    if (t == 0) out[65536] = 0.01f * load_loss + 0.01f * (var / mean);
  }
}

extern "C" void kernel_launch(void* const* d_in, const int* in_sizes, int n_in,
                              void* d_out, int out_size, void* d_ws, size_t ws_size,
                              hipStream_t stream) {
  (void)in_sizes; (void)n_in; (void)out_size; (void)ws_size;
  const float* x = (const float*)d_in[0];
  const float* noise = (const float*)d_in[1];
  const float* vol_w = (const float*)d_in[2];
  const float* vol_b = (const float*)d_in[3];
  const float* vol_g = (const float*)d_in[4];
  const float* vol_bb = (const float*)d_in[5];
  const float* trend_w = (const float*)d_in[6];
  const float* trend_b = (const float*)d_in[7];
  const float* trend_g = (const float*)d_in[8];
  const float* trend_bb = (const float*)d_in[9];
  const float* mom_w = (const float*)d_in[10];
  const float* mom_b = (const float*)d_in[11];
  const float* mom_g = (const float*)d_in[12];
  const float* mom_bb = (const float*)d_in[13];
  const float* reg_w = (const float*)d_in[14];
  const float* reg_b = (const float*)d_in[15];
  const float* reg_g = (const float*)d_in[16];
  const float* reg_bb = (const float*)d_in[17];
  const float* rc1_w = (const float*)d_in[18];
  const float* rc1_b = (const float*)d_in[19];
  const float* rc2_w = (const float*)d_in[20];
  const float* rc2_b = (const float*)d_in[21];
  const float* g1_w = (const float*)d_in[22];
  const float* g1_b = (const float*)d_in[23];
  const float* g1_g = (const float*)d_in[24];
  const float* g1_bb = (const float*)d_in[25];
  const float* g2_w = (const float*)d_in[26];
  const float* g2_b = (const float*)d_in[27];
  const float* g2_g = (const float*)d_in[28];
  const float* g2_bb = (const float*)d_in[29];
  const float* g3_w = (const float*)d_in[30];
  const float* g3_b = (const float*)d_in[31];
  const float* ns1_w = (const float*)d_in[32];
  const float* ns1_b = (const float*)d_in[33];
  const float* ns2_w = (const float*)d_in[34];
  const float* ns2_b = (const float*)d_in[35];
  const float* spec = (const float*)d_in[36];
  float* out = (float*)d_out;

  const size_t B = BROWS;
  float* ws = (float*)d_ws;
  float* rp4 = ws;                                    // B*4 f32
  float* nsc = rp4 + B * 4;                           // B f32
  float* z1 = nsc + B;                                // B*1160 f32
  unsigned short* gip = (unsigned short*)(z1 + B * 1160);  // B*1280 ush (KT=20)
  float* z2 = (float*)gip;                            // alias: B*580 f32 (gi dead after G1)
  unsigned short* z1p = gip + B * 1280;               // B*2432 ush (KT=38)
  unsigned short* w1p = z1p + B * 2432;               // 1280*1280 ush
  unsigned short* w2p = w1p + (size_t)1280 * 1280;    // 640*2432 ush
  unsigned short* wencp = w2p + (size_t)640 * 2432;   // 128*1024 ush
  float* wt = (float*)(wencp + 128 * 1024);           // 580*64 f32
  float* benc = wt + 580 * 64;                        // 64 f32
  float* pg = benc + 64;                              // 2048*64
  float* pl = pg + 2048 * 64;                         // 2048*64
  float* mfraw = pl + 2048 * 64;                      // B*64 f32

  hipFuncSetAttribute(reinterpret_cast<const void*>(gemm_fp16x3_v10),
                      hipFuncAttributeMaxDynamicSharedMemorySize, 49152);

  // prep: all splits + transposes (one launch)
  prep_kernel<<<5054, 256, 0, stream>>>(
      x, g1_w, w1p, g2_w, w2p, vol_w, trend_w, mom_w, reg_w, wencp,
      g3_w, wt, vol_b, trend_b, mom_b, reg_b, benc, gip);

  // encoder GEMM: [16384,512] x [64,512]^T -> mfraw ; grid 128 m x 1 n
  gemm_fp16x3_v10<<<128, 256, 49152, stream>>>(
      gip, wencp, benc, mfraw, 64, 16, 64, 1, 1280, 1024);

  // encoder post: ReLU+LN16+router+nsc + gi tail planes
  enc_post<<<1024, 256, 0, stream>>>(
      mfraw, vol_g, vol_bb, trend_g, trend_bb, mom_g, mom_bb, reg_g, reg_bb,
      rc1_w, rc1_b, rc2_w, rc2_b, ns1_w, ns1_b, ns2_w, ns2_b, rp4, nsc, gip);

  // G1: [16384,640] x [1280,640]^T -> z1 ; grid 128 m x 20 n = 2560 (8|2560)
  gemm_fp16x3_v10<<<2560, 256, 49152, stream>>>(
      gip, w1p, g1_b, z1, 1160, 20, 1160, 20, 1280, 1280);
  ln_gelu_split_v4<<<4096, 256, 0, stream>>>(z1, g1_g, g1_bb, z1p);

  // G2: [16384,1216] x [640,1216]^T -> z2 ; grid 128 m x 10 n = 1280 (8|1280)
  gemm_fp16x3_v10<<<1280, 256, 49152, stream>>>(
      z1p, w2p, g2_b, z2, 580, 38, 580, 10, 2432, 2432);

  // tail: LN+GELU+G3-GEMV+noisy-top2+partials (8 rows/block, shared Wt pass)
  tail_v3<<<2048, 256, 0, stream>>>(
      z2, g2_g, g2_bb, wt, g3_b, rp4, nsc, noise, spec, out, pg, pl);
  loss_kernel2<<<1, 1024, 0, stream>>>(pg, pl, out);
}

// Round 21
// 345.611 us; speedup vs baseline: 1.1679x; 1.0010x over previous
//
#include <hip/hip_runtime.h>
#include <hip/hip_fp16.h>
#include <cfloat>

#define BROWS 16384

typedef float f32x4 __attribute__((ext_vector_type(4)));
typedef _Float16 f16x8 __attribute__((ext_vector_type(8)));

// ---------- wave helpers ----------
__device__ __forceinline__ float wsum64(float v) {
#pragma unroll
  for (int off = 32; off; off >>= 1) v += __shfl_xor(v, off);
  return v;
}
__device__ __forceinline__ float wmax64(float v) {
#pragma unroll
  for (int off = 32; off; off >>= 1) v = fmaxf(v, __shfl_xor(v, off));
  return v;
}
__device__ __forceinline__ float gsum16(float v) {
#pragma unroll
  for (int off = 1; off < 16; off <<= 1) v += __shfl_xor(v, off);
  return v;
}

// exact-GELU via branchless A&S 7.1.26 erf (max abs err 1.5e-7 ~ fp32 noise)
__device__ __forceinline__ float gelu_exact(float y) {
  const float x = y * 0.70710678118654752f;
  const float ax = fabsf(x);
  const float t = 1.f / fmaf(0.3275911f, ax, 1.f);
  float p = fmaf(1.061405429f, t, -1.453152027f);
  p = fmaf(p, t, 1.421413741f);
  p = fmaf(p, t, -0.284496736f);
  p = fmaf(p, t, 0.254829592f);
  p = p * t;
  const float e = __expf(-ax * ax);
  const float er = fmaf(-p, e, 1.f);
  const float erfx = copysignf(er, x);
  return 0.5f * y * (1.f + erfx);
}

// fp16 2-limb split: v ~= h0 + 2^-11 * h1, residual <= 2^-24 |v|
__device__ __forceinline__ void split2(float v, unsigned short& o0, unsigned short& o1) {
  const _Float16 h0 = (_Float16)v;
  const float r = (v - (float)h0) * 2048.0f;
  const _Float16 h1 = (_Float16)r;
  o0 = __builtin_bit_cast(unsigned short, h0);
  o1 = __builtin_bit_cast(unsigned short, h1);
}

// async global -> LDS, 16B per lane, dest = wave-uniform base + lane*16
__device__ __forceinline__ void gll16(const unsigned short* g, unsigned short* l) {
  __builtin_amdgcn_global_load_lds(
      (const __attribute__((address_space(1))) unsigned int*)g,
      (__attribute__((address_space(3))) unsigned int*)l, 16, 0, 0);
}

// Combined swizzled plane format (2 fp16 limbs):
//   buf[(r*KT + kt)*64 + p*8 + s], physical chunk p = c ^ (r&7);
//   c 0..3 = limb0, c 4..7 = limb1. Conflict-free ds_read_b128.
__device__ __forceinline__ void write_chunks(
    unsigned short* __restrict__ P, size_t row, int KT, int kt, int c,
    const float* vals8) {
  unsigned short h0[8], h1[8];
#pragma unroll
  for (int s = 0; s < 8; ++s) split2(vals8[s], h0[s], h1[s]);
  const int r7 = (int)(row & 7);
  const size_t o = ((size_t)row * KT + kt) * 64;
  *(uint4*)&P[o + (size_t)((c ^ r7) * 8)] = *(const uint4*)h0;
  *(uint4*)&P[o + (size_t)(((4 + c) ^ r7) * 8)] = *(const uint4*)h1;
}

// ---------- 0) prep: all weight/x splits in one launch ----------
__device__ __forceinline__ void split_w_body(
    const float* __restrict__ W, unsigned short* __restrict__ P,
    unsigned idx, int Nreal, int Kreal, int KT) {
  const unsigned ipr = (unsigned)(KT * 4);
  const unsigned row = idx / ipr;
  const unsigned item = idx - row * ipr;
  const int kt = item >> 2, c = item & 3;
  float v[8];
#pragma unroll
  for (int s = 0; s < 8; ++s) {
    const int k = kt * 32 + c * 8 + s;
    v[s] = ((int)row < Nreal && k < Kreal) ? W[(size_t)row * Kreal + k] : 0.f;
  }
  write_chunks(P, row, KT, kt, c, v);
}

__global__ __launch_bounds__(256) void prep_kernel(
    const float* __restrict__ x,
    const float* __restrict__ W1, unsigned short* __restrict__ P1,
    const float* __restrict__ W2, unsigned short* __restrict__ P2,
    const float* __restrict__ vol_w, const float* __restrict__ trend_w,
    const float* __restrict__ mom_w, const float* __restrict__ reg_w,
    unsigned short* __restrict__ Pe,
    const float* __restrict__ W3, float* __restrict__ Wt,
    const float* __restrict__ vol_b, const float* __restrict__ trend_b,
    const float* __restrict__ mom_b, const float* __restrict__ reg_b,
    float* __restrict__ benc,
    unsigned short* __restrict__ gip) {
  const unsigned bid = blockIdx.x;
  const int t = threadIdx.x;
  if (bid < 380) {        // W1: Npad=1216, KT=20 -> 1216*80/256 = 380 blocks
    split_w_body(W1, P1, bid * 256 + t, 1160, 580, 20);
  } else if (bid < 760) { // W2: Npad=640, KT=38
    split_w_body(W2, P2, (bid - 380) * 256 + t, 580, 1160, 38);
  } else if (bid < 792) { // Wenc: Npad=128, KT=16
    const unsigned idx = (bid - 760) * 256 + t;  // < 8192 = 128*64
    const unsigned row = idx >> 6;
    const unsigned item = idx & 63;
    const int kt = (int)(item >> 2), c = (int)(item & 3);
    float v[8];
    const float* wsrc = nullptr;
    if (row < 64) {
      const int br = (int)(row >> 4);
      wsrc = (br == 0) ? vol_w : (br == 1) ? trend_w : (br == 2) ? mom_w : reg_w;
      wsrc += (size_t)(row & 15) * 512;
    }
#pragma unroll
    for (int s = 0; s < 8; ++s) {
      const int k = kt * 32 + c * 8 + s;
      v[s] = wsrc ? wsrc[k] : 0.f;
    }
    write_chunks(Pe, row, 16, kt, c, v);
  } else if (bid < 937) { // W3 transpose: Wt[k][n] = W3[n][k], 580x64
    const unsigned idx = (bid - 792) * 256 + t;  // < 37120
    const unsigned k = idx >> 6, n = idx & 63;
    Wt[k * 64 + n] = W3[(size_t)n * 580 + k];
  } else if (bid == 937) { // benc: concat branch biases
    if (t < 64) {
      const int br = t >> 4;
      const float* bsel = (br == 0) ? vol_b : (br == 1) ? trend_b : (br == 2) ? mom_b : reg_b;
      benc[t] = bsel[t & 15];
    }
  } else {                // x -> gi planes kt 0..15
    const unsigned idx = (bid - 938) * 256 + t;  // < 16384*64
    const unsigned row = idx >> 6;
    const unsigned item = idx & 63;
    const int kt = (int)(item >> 2), c = (int)(item & 3);
    const int kbase = kt * 32 + c * 8;
    float v[8];
    const float4 u0 = *(const float4*)(x + (size_t)row * 512 + kbase);
    const float4 u1 = *(const float4*)(x + (size_t)row * 512 + kbase + 4);
    v[0] = u0.x; v[1] = u0.y; v[2] = u0.z; v[3] = u0.w;
    v[4] = u1.x; v[5] = u1.y; v[6] = u1.z; v[7] = u1.w;
    write_chunks(gip, row, 20, kt, c, v);
  }
}

// ---------- 1) fp16x3 MFMA GEMM v10: 128x64 tile, 48KB LDS -> 3 blocks/CU ----------
__global__ __launch_bounds__(256, 3) void gemm_fp16x3_v10(
    const unsigned short* __restrict__ Ap, const unsigned short* __restrict__ Bp,
    const float* __restrict__ bias, float* __restrict__ C,
    int N, int KT, int ldc, int nbx, int strideA, int strideB) {
  extern __shared__ __align__(16) unsigned short smem[];  // 2 * 12288 ushorts
  const int t = threadIdx.x;
  const int wg = (blockIdx.x & 7) * ((int)gridDim.x >> 3) + (blockIdx.x >> 3);
  const int bx = wg % nbx, by = wg / nbx;
  const int m0 = by * 128, n0 = bx * 64;
  const int w = t >> 6, l = t & 63;
  const int lr = l & 15, lc = l >> 4;
  const int wm = (w >> 1) * 64, wn = (w & 1) * 32;

  size_t aoff[4], boff[2];
#pragma unroll
  for (int c = 0; c < 4; ++c) {
    const int rb = w * 32 + c * 8;
    aoff[c] = (size_t)(m0 + rb + (l >> 3)) * (size_t)strideA + (size_t)((l & 7) * 8);
  }
#pragma unroll
  for (int c = 0; c < 2; ++c) {
    const int rb = w * 16 + c * 8;
    boff[c] = (size_t)(n0 + rb + (l >> 3)) * (size_t)strideB + (size_t)((l & 7) * 8);
  }

  f32x4 accM[4][2], accL[4][2];
#pragma unroll
  for (int i = 0; i < 4; ++i)
#pragma unroll
    for (int j = 0; j < 2; ++j) {
      accM[i][j] = (f32x4){0.f, 0.f, 0.f, 0.f};
      accL[i][j] = (f32x4){0.f, 0.f, 0.f, 0.f};
    }

  auto stage = [&](int kt, int slot) {
    unsigned short* base = smem + slot * 12288;
    const size_t ko = (size_t)kt * 64;
#pragma unroll
    for (int c = 0; c < 4; ++c)
      gll16(Ap + aoff[c] + ko, base + (w * 32 + c * 8) * 64);
#pragma unroll
    for (int c = 0; c < 2; ++c)
      gll16(Bp + boff[c] + ko, base + 8192 + (w * 16 + c * 8) * 64);
  };

  stage(0, 0);
  __builtin_amdgcn_sched_barrier(0);
  int cur = 0;
  for (int kt = 0; kt < KT; ++kt) {
    __builtin_amdgcn_sched_barrier(0);
    if (kt + 1 < KT) {
      stage(kt + 1, cur ^ 1);               // writes the OTHER slot
      __builtin_amdgcn_sched_barrier(0);    // pin: stage issued before the count
      asm volatile("s_waitcnt vmcnt(6)" ::: "memory");  // stage(kt) landed
    } else {
      asm volatile("s_waitcnt vmcnt(0)" ::: "memory");
    }
    __builtin_amdgcn_sched_barrier(0);
    __builtin_amdgcn_s_barrier();           // all waves' stage(kt) visible
    __builtin_amdgcn_sched_barrier(0);

    const unsigned short* base = smem + cur * 12288;
    f16x8 a0[4], a1[4], b0[2], b1[2];
#pragma unroll
    for (int i = 0; i < 4; ++i) {
      const int ar = wm + i * 16 + lr;
      const int r7 = ar & 7;
      a0[i] = *(const f16x8*)&base[ar * 64 + ((lc ^ r7) << 3)];
      a1[i] = *(const f16x8*)&base[ar * 64 + (((4 + lc) ^ r7) << 3)];
    }
#pragma unroll
    for (int j = 0; j < 2; ++j) {
      const int brj = wn + j * 16 + lr;
      const int r7 = brj & 7;
      b0[j] = *(const f16x8*)&base[8192 + brj * 64 + ((lc ^ r7) << 3)];
      b1[j] = *(const f16x8*)&base[8192 + brj * 64 + (((4 + lc) ^ r7) << 3)];
    }
    __builtin_amdgcn_s_setprio(1);
#pragma unroll
    for (int i = 0; i < 4; ++i)
#pragma unroll
      for (int j = 0; j < 2; ++j)
        accM[i][j] = __builtin_amdgcn_mfma_f32_16x16x32_f16(a0[i], b0[j], accM[i][j], 0, 0, 0);
#pragma unroll
    for (int i = 0; i < 4; ++i)
#pragma unroll
      for (int j = 0; j < 2; ++j)
        accL[i][j] = __builtin_amdgcn_mfma_f32_16x16x32_f16(a1[i], b0[j], accL[i][j], 0, 0, 0);
#pragma unroll
    for (int i = 0; i < 4; ++i)
#pragma unroll
      for (int j = 0; j < 2; ++j)
        accL[i][j] = __builtin_amdgcn_mfma_f32_16x16x32_f16(a0[i], b1[j], accL[i][j], 0, 0, 0);
    __builtin_amdgcn_s_setprio(0);
    __builtin_amdgcn_sched_barrier(0);
    __builtin_amdgcn_s_barrier();           // WAR: all done reading cur
    __builtin_amdgcn_sched_barrier(0);      // pin: next iter's stage stays below
    cur ^= 1;
  }
  // epilogue: D layout col(lane&15)=n, row((lane>>4)*4+reg)=m
#pragma unroll
  for (int j = 0; j < 2; ++j) {
    const int n = n0 + wn + j * 16 + lr;
    if (n < N) {
      const float bz = bias[n];
#pragma unroll
      for (int i = 0; i < 4; ++i) {
        const int mb = m0 + wm + i * 16 + lc * 4;
#pragma unroll
        for (int r = 0; r < 4; ++r)
          C[(size_t)(mb + r) * (size_t)ldc + n] =
              accM[i][j][r] + 0.00048828125f * accL[i][j][r] + bz;
      }
    }
  }
}

// ---------- 1b) encoder post: ReLU+LN16+router+nsc + gi tail planes ----------
__global__ __launch_bounds__(256) void enc_post(
    const float* __restrict__ mfraw,
    const float* __restrict__ vol_g, const float* __restrict__ vol_bb,
    const float* __restrict__ trend_g, const float* __restrict__ trend_bb,
    const float* __restrict__ mom_g, const float* __restrict__ mom_bb,
    const float* __restrict__ reg_g, const float* __restrict__ reg_bb,
    const float* __restrict__ rc1_w, const float* __restrict__ rc1_b,
    const float* __restrict__ rc2_w, const float* __restrict__ rc2_b,
    const float* __restrict__ ns1_w, const float* __restrict__ ns1_b,
    const float* __restrict__ ns2_w, const float* __restrict__ ns2_b,
    float* __restrict__ rp4, float* __restrict__ nsc,
    unsigned short* __restrict__ gip) {
  __shared__ float smf[16][64];
  __shared__ float shid[16][32];
  __shared__ float srp[16][4];
  const int t = threadIdx.x, w = t >> 6, e = t & 63;
  const int br = e >> 4;
  const int rowbase0 = blockIdx.x * 16;

  const float* gsel = (br == 0) ? vol_g : (br == 1) ? trend_g : (br == 2) ? mom_g : reg_g;
  const float* bbsel = (br == 0) ? vol_bb : (br == 1) ? trend_bb : (br == 2) ? mom_bb : reg_bb;
  const float gv = gsel[e & 15];
  const float bbv = bbsel[e & 15];
#pragma unroll
  for (int r = 0; r < 4; ++r) {
    const int row = w * 4 + r;
    const float raw = mfraw[(size_t)(rowbase0 + row) * 64 + e];
    const float v = fmaxf(raw, 0.f);
    const float mu = gsum16(v) * (1.f / 16.f);
    const float d = v - mu;
    const float var = gsum16(d * d) * (1.f / 16.f);
    smf[row][e] = d * (1.f / sqrtf(var + 1e-5f)) * gv + bbv;
  }
  __syncthreads();

  if (e < 32) {
#pragma unroll
    for (int r = 0; r < 4; ++r) {
      const int row = w * 4 + r;
      float h = rc1_b[e];
#pragma unroll 8
      for (int j = 0; j < 64; ++j) h += rc1_w[e * 64 + j] * smf[row][j];
      shid[row][e] = fmaxf(h, 0.f);
    }
  }
  __syncthreads();
  if (e < 16) {
    const int r = e >> 2, l = e & 3;
    const int row = w * 4 + r;
    float z = rc2_b[l];
#pragma unroll 8
    for (int j = 0; j < 32; ++j) z += rc2_w[l * 32 + j] * shid[row][j];
    float mx = z;
    mx = fmaxf(mx, __shfl_xor(mx, 1));
    mx = fmaxf(mx, __shfl_xor(mx, 2));
    const float ex = expf(z - mx);
    float s = ex;
    s += __shfl_xor(s, 1);
    s += __shfl_xor(s, 2);
    const float rp = ex / s;
    srp[row][l] = rp;
    rp4[(size_t)(rowbase0 + row) * 4 + l] = rp;
  }
  __syncthreads();
  if (e < 4) {
    const int row = w * 4 + e;
    const float rp0 = srp[row][0], rp1 = srp[row][1], rp2 = srp[row][2], rp3 = srp[row][3];
    float z = ns2_b[0];
#pragma unroll
    for (int i = 0; i < 16; ++i) {
      float h = ns1_b[i] + ns1_w[i * 4 + 0] * rp0 + ns1_w[i * 4 + 1] * rp1 +
                ns1_w[i * 4 + 2] * rp2 + ns1_w[i * 4 + 3] * rp3;
      z += ns2_w[i] * fmaxf(h, 0.f);
    }
    nsc[rowbase0 + row] = 1.f / (1.f + expf(-z));
  }
  __syncthreads();
  // gi tail planes (kt 16..19): 16 rows x 16 items = 256 -> one per thread
  {
    const int rib = t >> 4;
    const int item = t & 15;
    const int kt = 16 + (item >> 2), c = item & 3;
    const int kbase = kt * 32 + c * 8;
    const size_t grow = (size_t)rowbase0 + rib;
    float v[8];
#pragma unroll
    for (int s = 0; s < 8; ++s) {
      const int k = kbase + s;
      float f = 0.f;
      if (k < 576) f = smf[rib][k - 512];
      else if (k < 580) f = srp[rib][k - 576];
      v[s] = f;
    }
    write_chunks(gip, grow, 20, kt, c, v);
  }
}

// ---------- 2) tail v3: 8 rows/block, k-split GEMV with shared Wt pass ----------
__global__ __launch_bounds__(256) void tail_v3(
    const float* __restrict__ Zraw, const float* __restrict__ gamma,
    const float* __restrict__ beta, const float* __restrict__ Wt,
    const float* __restrict__ bias,
    const float* __restrict__ rp4, const float* __restrict__ nsc,
    const float* __restrict__ noise, const float* __restrict__ spec,
    float* __restrict__ out, float* __restrict__ pg, float* __restrict__ pl) {
  __shared__ __align__(16) float arowT[580][12];
  __shared__ float spart[4][8][64];
  __shared__ float sgp[4][64], slp[4][64];
  const int t = threadIdx.x, w = t >> 6, e = t & 63;

  // ph1: LN + GELU for this wave's 2 rows
#pragma unroll
  for (int rr = 0; rr < 2; ++rr) {
    const int r = w * 2 + rr;
    const int row = blockIdx.x * 8 + r;
    const float* zr = Zraw + (size_t)row * 580;
    float vals[10];
    float s = 0.f, ss = 0.f;
#pragma unroll
    for (int c = 0; c < 10; ++c) {
      const int k = e + c * 64;
      const float v = (k < 580) ? zr[k] : 0.f;
      vals[c] = v;
      s += v;
      ss += v * v;
    }
    s = wsum64(s);
    ss = wsum64(ss);
    const float mu = s * (1.f / 580.f);
    const float var = fmaxf(ss * (1.f / 580.f) - mu * mu, 0.f);
    const float rs = 1.f / sqrtf(var + 1e-5f);
#pragma unroll
    for (int c = 0; c < 10; ++c) {
      const int k = e + c * 64;
      if (k < 580)
        arowT[k][r] = gelu_exact((vals[c] - mu) * rs * gamma[k] + beta[k]);
    }
  }
  __syncthreads();

  // ph2: k-split GEMV
  float part[8] = {};
  const int k0 = w * 145;
#pragma unroll 4
  for (int kk = 0; kk < 145; ++kk) {
    const int k = k0 + kk;
    const float4 a0 = *(const float4*)&arowT[k][0];
    const float4 a1 = *(const float4*)&arowT[k][4];
    const float wv = Wt[k * 64 + e];
    part[0] = fmaf(a0.x, wv, part[0]);
    part[1] = fmaf(a0.y, wv, part[1]);
    part[2] = fmaf(a0.z, wv, part[2]);
    part[3] = fmaf(a0.w, wv, part[3]);
    part[4] = fmaf(a1.x, wv, part[4]);
    part[5] = fmaf(a1.y, wv, part[5]);
    part[6] = fmaf(a1.z, wv, part[6]);
    part[7] = fmaf(a1.w, wv, part[7]);
  }
#pragma unroll
  for (int r = 0; r < 8; ++r) spart[w][r][e] = part[r];
  __syncthreads();

  // ph3: finish this wave's 2 rows
  const float4 sp = *(const float4*)(spec + e * 4);
  const float bz = bias[e];
  float accg = 0.f, accl = 0.f;
#pragma unroll
  for (int rr = 0; rr < 2; ++rr) {
    const int r = w * 2 + rr;
    const int row = blockIdx.x * 8 + r;
    float c = bz + ((spart[0][r][e] + spart[1][r][e]) + (spart[2][r][e] + spart[3][r][e]));
    const float4 rp = *(const float4*)(rp4 + (size_t)row * 4);
    c += rp.x * sp.x + rp.y * sp.y + rp.z * sp.z + rp.w * sp.w;
    const float nv = noise[(size_t)row * 64 + e];
    const float noisy = c + nv * nsc[row];
    float v = noisy;
    int ix = e;
#pragma unroll
    for (int off = 32; off; off >>= 1) {
      const float ov = __shfl_xor(v, off);
      const int oi = __shfl_xor(ix, off);
      if (ov > v || (ov == v && oi < ix)) { v = ov; ix = oi; }
    }
    const float v1 = v;
    const int i1 = ix;
    float v2 = (e == i1) ? -FLT_MAX : noisy;
    int ix2 = e;
#pragma unroll
    for (int off = 32; off; off >>= 1) {
      const float ov = __shfl_xor(v2, off);
      const int oi = __shfl_xor(ix2, off);
      if (ov > v2 || (ov == v2 && oi < ix2)) { v2 = ov; ix2 = oi; }
    }
    const int i2 = ix2;
    if (e == 0) {
      const float texp = expf(v2 - v1);
      const float tw0 = 1.f / (1.f + texp);
      out[(size_t)row * 2 + 0] = tw0;
      out[(size_t)row * 2 + 1] = texp * tw0;
      out[32768 + (size_t)row * 2 + 0] = (float)i1;
      out[32768 + (size_t)row * 2 + 1] = (float)i2;
    }
    const float mx = wmax64(c);
    const float p = expf(c - mx);
    const float ssum = wsum64(p);
    accg += p / ssum;
    accl += (e == i1 || e == i2) ? 1.f : 0.f;
  }
  sgp[w][e] = accg;
  slp[w][e] = accl;
  __syncthreads();
  if (t < 64) {
    pg[blockIdx.x * 64 + t] = sgp[0][t] + sgp[1][t] + sgp[2][t] + sgp[3][t];
    pl[blockIdx.x * 64 + t] = slp[0][t] + slp[1][t] + slp[2][t] + slp[3][t];
  }
}

// ---------- 3) ln_gelu_split v4: register-resident, no LDS, no barriers ----------
__global__ __launch_bounds__(256) void ln_gelu_split_v4(
    const float* __restrict__ Z, const float* __restrict__ gamma,
    const float* __restrict__ beta, unsigned short* __restrict__ P) {
  const int N = 1160, KT = 38;
  const int t = threadIdx.x, w = t >> 6, l = t & 63;
  const size_t row = (size_t)blockIdx.x * 4 + w;
  const float* zr = Z + row * N;
  float vals[3][8];
  float s = 0.f;
#pragma unroll
  for (int c = 0; c < 3; ++c) {
    const int ch = l + c * 64;
    if (ch < 145) {
      const float4 u0 = *(const float4*)(zr + ch * 8);
      const float4 u1 = *(const float4*)(zr + ch * 8 + 4);
      vals[c][0] = u0.x; vals[c][1] = u0.y; vals[c][2] = u0.z; vals[c][3] = u0.w;
      vals[c][4] = u1.x; vals[c][5] = u1.y; vals[c][6] = u1.z; vals[c][7] = u1.w;
      s += ((u0.x + u0.y) + (u0.z + u0.w)) + ((u1.x + u1.y) + (u1.z + u1.w));
    } else {
#pragma unroll
      for (int k = 0; k < 8; ++k) vals[c][k] = 0.f;
    }
  }
  s = wsum64(s);
  const float mu = s * (1.f / 1160.f);
  float q = 0.f;
#pragma unroll
  for (int c = 0; c < 3; ++c) {
    const int ch = l + c * 64;
    if (ch < 145) {
#pragma unroll
      for (int k = 0; k < 8; ++k) {
        const float d = vals[c][k] - mu;
        q += d * d;
      }
    }
  }
  q = wsum64(q);
  const float rstd = 1.f / sqrtf(q * (1.f / 1160.f) + 1e-5f);
#pragma unroll
  for (int c = 0; c < 3; ++c) {
    const int ch = l + c * 64;
    if (ch < 152) {
      float g[8];
      if (ch < 145) {
        const int kb = ch * 8;
#pragma unroll
        for (int k = 0; k < 8; ++k)
          g[k] = gelu_exact((vals[c][k] - mu) * rstd * gamma[kb + k] + beta[kb + k]);
      } else {
#pragma unroll
        for (int k = 0; k < 8; ++k) g[k] = 0.f;
      }
      write_chunks(P, row, KT, ch >> 2, ch & 3, g);
    }
  }
}

// ---------- 5) aux loss (hierarchical over 2048 block-partials) ----------
__global__ __launch_bounds__(1024) void loss_kernel2(
    const float* __restrict__ pg, const float* __restrict__ pl,
    float* __restrict__ out) {
  __shared__ float sgl[16][64], sll[16][64];
  const int t = threadIdx.x, w = t >> 6, e = t & 63;
  float g = 0.f, l = 0.f;
  for (int b = w; b < 2048; b += 16) {
    g += pg[b * 64 + e];
    l += pl[b * 64 + e];
  }
  sgl[w][e] = g;
  sll[w][e] = l;
  __syncthreads();
  if (t < 64) {
    float gg = 0.f, ll = 0.f;
#pragma unroll
    for (int i = 0; i < 16; ++i) { gg += sgl[i][t]; ll += sll[i][t]; }
    const float prob = gg * (1.f / 16384.f);
    const float ld = ll * (1.f / 16384.f);
    const float load_loss = 64.f * wsum64(prob * ld);
    const float sgs = wsum64(gg);
    const float mean = sgs * (1.f / 64.f);
    const float d = gg - mean;
    const float var = wsum64(d * d) * (1.f / 63.f);
    if (t == 0) out[65536] = 0.01f * load_loss + 0.01f * (var / mean);
  }
}

extern "C" void kernel_launch(void* const* d_in, const int* in_sizes, int n_in,
                              void* d_out, int out_size, void* d_ws, size_t ws_size,
                              hipStream_t stream) {
  (void)in_sizes; (void)n_in; (void)out_size; (void)ws_size;
  const float* x = (const float*)d_in[0];
  const float* noise = (const float*)d_in[1];
  const float* vol_w = (const float*)d_in[2];
  const float* vol_b = (const float*)d_in[3];
  const float* vol_g = (const float*)d_in[4];
  const float* vol_bb = (const float*)d_in[5];
  const float* trend_w = (const float*)d_in[6];
  const float* trend_b = (const float*)d_in[7];
  const float* trend_g = (const float*)d_in[8];
  const float* trend_bb = (const float*)d_in[9];
  const float* mom_w = (const float*)d_in[10];
  const float* mom_b = (const float*)d_in[11];
  const float* mom_g = (const float*)d_in[12];
  const float* mom_bb = (const float*)d_in[13];
  const float* reg_w = (const float*)d_in[14];
  const float* reg_b = (const float*)d_in[15];
  const float* reg_g = (const float*)d_in[16];
  const float* reg_bb = (const float*)d_in[17];
  const float* rc1_w = (const float*)d_in[18];
  const float* rc1_b = (const float*)d_in[19];
  const float* rc2_w = (const float*)d_in[20];
  const float* rc2_b = (const float*)d_in[21];
  const float* g1_w = (const float*)d_in[22];
  const float* g1_b = (const float*)d_in[23];
  const float* g1_g = (const float*)d_in[24];
  const float* g1_bb = (const float*)d_in[25];
  const float* g2_w = (const float*)d_in[26];
  const float* g2_b = (const float*)d_in[27];
  const float* g2_g = (const float*)d_in[28];
  const float* g2_bb = (const float*)d_in[29];
  const float* g3_w = (const float*)d_in[30];
  const float* g3_b = (const float*)d_in[31];
  const float* ns1_w = (const float*)d_in[32];
  const float* ns1_b = (const float*)d_in[33];
  const float* ns2_w = (const float*)d_in[34];
  const float* ns2_b = (const float*)d_in[35];
  const float* spec = (const float*)d_in[36];
  float* out = (float*)d_out;

  const size_t B = BROWS;
  float* ws = (float*)d_ws;
  float* rp4 = ws;                                    // B*4 f32
  float* nsc = rp4 + B * 4;                           // B f32
  float* z1 = nsc + B;                                // B*1160 f32
  unsigned short* gip = (unsigned short*)(z1 + B * 1160);  // B*1280 ush (KT=20)
  float* z2 = (float*)gip;                            // alias: B*580 f32 (gi dead after G1)
  unsigned short* z1p = gip + B * 1280;               // B*2432 ush (KT=38)
  unsigned short* w1p = z1p + B * 2432;               // 1216*1280 ush
  unsigned short* w2p = w1p + (size_t)1216 * 1280;    // 640*2432 ush
  unsigned short* wencp = w2p + (size_t)640 * 2432;   // 128*1024 ush
  float* wt = (float*)(wencp + 128 * 1024);           // 580*64 f32
  float* benc = wt + 580 * 64;                        // 64 f32
  float* pg = benc + 64;                              // 2048*64
  float* pl = pg + 2048 * 64;                         // 2048*64
  float* mfraw = pl + 2048 * 64;                      // B*64 f32

  hipFuncSetAttribute(reinterpret_cast<const void*>(gemm_fp16x3_v10),
                      hipFuncAttributeMaxDynamicSharedMemorySize, 49152);

  // prep: all splits + transposes (one launch)
  prep_kernel<<<5034, 256, 0, stream>>>(
      x, g1_w, w1p, g2_w, w2p, vol_w, trend_w, mom_w, reg_w, wencp,
      g3_w, wt, vol_b, trend_b, mom_b, reg_b, benc, gip);

  // encoder GEMM: [16384,512] x [64,512]^T -> mfraw ; grid 128 m x 1 n
  gemm_fp16x3_v10<<<128, 256, 49152, stream>>>(
      gip, wencp, benc, mfraw, 64, 16, 64, 1, 1280, 1024);

  // encoder post: ReLU+LN16+router+nsc + gi tail planes
  enc_post<<<1024, 256, 0, stream>>>(
      mfraw, vol_g, vol_bb, trend_g, trend_bb, mom_g, mom_bb, reg_g, reg_bb,
      rc1_w, rc1_b, rc2_w, rc2_b, ns1_w, ns1_b, ns2_w, ns2_b, rp4, nsc, gip);

  // G1: [16384,640] x [1216,640]^T -> z1 ; grid 128 m x 19 n = 2432 (8|2432)
  gemm_fp16x3_v10<<<2432, 256, 49152, stream>>>(
      gip, w1p, g1_b, z1, 1160, 20, 1160, 19, 1280, 1280);
  ln_gelu_split_v4<<<4096, 256, 0, stream>>>(z1, g1_g, g1_bb, z1p);

  // G2: [16384,1216] x [640,1216]^T -> z2 ; grid 128 m x 10 n = 1280 (8|1280)
  gemm_fp16x3_v10<<<1280, 256, 49152, stream>>>(
      z1p, w2p, g2_b, z2, 580, 38, 580, 10, 2432, 2432);

  // tail: LN+GELU+G3-GEMV+noisy-top2+partials (8 rows/block, shared Wt pass)
  tail_v3<<<2048, 256, 0, stream>>>(
      z2, g2_g, g2_bb, wt, g3_b, rp4, nsc, noise, spec, out, pg, pl);
  loss_kernel2<<<1, 1024, 0, stream>>>(pg, pl, out);
}